// Round 12
// baseline (256.376 us; speedup 1.0000x reference)
//
#include <hip/hip_runtime.h>

typedef unsigned int uint32;
using half2v  = __attribute__((ext_vector_type(2))) _Float16;
using half4v  = __attribute__((ext_vector_type(4))) _Float16;
using half8   = __attribute__((ext_vector_type(8))) _Float16;
using floatx4 = __attribute__((ext_vector_type(4))) float;

__device__ __forceinline__ float sigm_f(float x){
  return __builtin_amdgcn_rcpf(1.0f + __expf(-x));
}
__device__ __forceinline__ float silu_f(float x){ return x * sigm_f(x); }

__device__ __forceinline__ half2v pkrtz(float a, float b){
  return __builtin_bit_cast(half2v, __builtin_amdgcn_cvt_pkrtz(a, b));
}

// async global->LDS, 16B per lane, zero VGPR cost. dst is wave-uniform base;
// HW writes lane i at dst + i*16B. src is per-lane.
__device__ __forceinline__ void gll16(const _Float16* src, _Float16* ldsDst){
  __builtin_amdgcn_global_load_lds(
      (const __attribute__((address_space(1))) uint32*)src,
      (__attribute__((address_space(3))) uint32*)ldsDst, 16, 0, 0);
}

// ---------------------------------------------------------------------------
// fp16 weight blob layout (element offsets): see previous rounds.
// ---------------------------------------------------------------------------
#define OFF_W2    196608
#define OFF_HEAD  307200
#define OFF_WDT   330240
#define OFF_ROBJ  340608
#define OFF_DWB   345216
#define WTOT      346368

// padded expand buffer, CHANNEL-GROUP-MAJOR: per branch [g=24][pp=143552][8ch]
#define PPOS 143552L
#define EXPAD_ELEMS 27561984L   // 24*143552*8
// stem output, CHANNEL-GROUP-MAJOR: [g=12][n=134400][8ch]
#define NDW  134400L

__global__ __launch_bounds__(256) void wconv_k(
    const float* __restrict__ s0, const float* __restrict__ s1,
    const float* __restrict__ s2, const float* __restrict__ cw1,
    const float* __restrict__ rw1, const float* __restrict__ cw2,
    const float* __restrict__ rw2, const float* __restrict__ chw,
    const float* __restrict__ cwd, const float* __restrict__ rwd,
    const float* __restrict__ rpw, const float* __restrict__ opw,
    const float* __restrict__ cbd, const float* __restrict__ rbd,
    _Float16* __restrict__ dst)
{
  int i = blockIdx.x*256 + threadIdx.x;
  if (i >= WTOT) return;
  float v;
  if (i < OFF_WDT) {
    const float* p; int off;
    if      (i < 12288)  { p = s0;  off = i; }
    else if (i < 36864)  { p = s1;  off = i - 12288; }
    else if (i < 86016)  { p = s2;  off = i - 36864; }
    else if (i < 141312) { p = cw1; off = i - 86016; }
    else if (i < 196608) { p = rw1; off = i - 141312; }
    else if (i < 251904) { p = cw2; off = i - 196608; }
    else if (i < 307200) { p = rw2; off = i - 251904; }
    else                 { p = chw; off = i - 307200; }
    v = p[off];
  } else if (i < OFF_ROBJ) {
    int rel = i - OFF_WDT;
    int br = rel / 5184; int r2 = rel - br*5184;
    int lvl = r2 / 1728; int r3 = r2 - lvl*1728;
    int j = r3 / 192;    int c = r3 - j*192;
    const float* wd = br ? rwd : cwd;
    v = wd[lvl*1728 + c*9 + j];
  } else if (i < OFF_DWB) {
    int rel = i - OFF_ROBJ;
    int lvl = rel / 1536; int r2 = rel - lvl*1536;
    int co = r2 / 96;     int k = r2 - co*96;
    v = (co < 4) ? rpw[lvl*384 + co*96 + k] : (co == 4 ? opw[lvl*96 + k] : 0.f);
  } else {
    int rel = i - OFF_DWB;
    int br = rel / 576;  int r2 = rel - br*576;
    int lvl = r2 / 192;  int c = r2 - lvl*192;
    v = (br ? rbd : cbd)[lvl*192 + c];
  }
  dst[i] = (_Float16)v;
}

// ---------------------------------------------------------------------------
// Zero the 1-pixel border of the padded expand buffers (channel-major).
// ---------------------------------------------------------------------------
__global__ __launch_bounds__(256) void zpad_k(_Float16* __restrict__ exBase)
{
  int ci = blockIdx.x*256 + threadIdx.x;
  if (ci >= 439296) return;
  int br = ci / 219648; int r = ci - br*219648;
  int W, PLB, rem, perimg;
  if (r < 124416)      { W=80; PLB=0;      rem = r;          perimg = 7776; }
  else if (r < 187392) { W=40; PLB=107584; rem = r - 124416; perimg = 3936; }
  else                 { W=20; PLB=135808; rem = r - 187392; perimg = 2016; }
  int b = rem / perimg; int t3 = rem - b*perimg;
  int p = t3 / 24; int g = t3 - p*24;
  int PW = W + 2;
  int row, col;
  if (p < 2*PW) { row = (p >= PW) ? (W+1) : 0; col = (p >= PW) ? (p - PW) : p; }
  else { int q = p - 2*PW; row = 1 + (q >> 1); col = (q & 1) ? (W+1) : 0; }
  long pp = (long)PLB + (long)b*PW*PW + row*PW + col;
  half8 z = {(_Float16)0,(_Float16)0,(_Float16)0,(_Float16)0,
             (_Float16)0,(_Float16)0,(_Float16)0,(_Float16)0};
  *(half8*)(exBase + br*EXPAD_ELEMS + ((long)g*PPOS + pp)*8) = z;
}

// ---------------------------------------------------------------------------
// Stem GEMM from NCHW fp32, fp16 MFMA. Output CHANNEL-GROUP-MAJOR [g][n][8].
// ---------------------------------------------------------------------------
__global__ __launch_bounds__(256) void stem_k(
    const float* __restrict__ x0, const float* __restrict__ x1,
    const float* __restrict__ x2, const _Float16* __restrict__ Wb,
    const float* __restrict__ sb0, const float* __restrict__ sb1,
    const float* __restrict__ sb2, _Float16* __restrict__ Out)
{
  const int m0 = blockIdx.x << 7;
  const int lvl = (m0 < 102400) ? 0 : (m0 < 128000 ? 1 : 2);
  const int CIN = (lvl==0)?128:(lvl==1?256:512);
  const int HW  = (lvl==0)?6400:(lvl==1?1600:400);
  const int noff= (lvl==0)?0:(lvl==1?102400:128000);
  const float* X = (lvl==0)?x0:(lvl==1?x1:x2);
  const _Float16* Wl = Wb + ((lvl==0)?0:(lvl==1?12288:36864));
  const float* bias = (lvl==0)?sb0:(lvl==1?sb1:sb2);

  int t=threadIdx.x, lane=t&63, wv=t>>6, mr=lane&15, quad=lane>>4;

  int idx[2];
  #pragma unroll
  for (int nt=0; nt<2; ++nt) {
    int n = m0 + wv*32 + nt*16 + mr;
    int m = n - noff; int b_ = m / HW; int p = m - b_*HW;
    idx[nt] = (b_*CIN + quad*8)*HW + p;
  }
  const _Float16* Ap = Wl + mr*CIN + quad*8;

  floatx4 zero = {0.f,0.f,0.f,0.f};
  floatx4 acc[6][2];
  #pragma unroll
  for (int i=0;i<6;++i)
    #pragma unroll
    for (int j=0;j<2;++j) acc[i][j] = zero;

  for (int k=0; k<CIN; k+=32) {
    half8 a[6], b[2];
    #pragma unroll
    for (int mt=0; mt<6; ++mt) a[mt] = *(const half8*)(Ap + mt*16*CIN);
    #pragma unroll
    for (int nt=0; nt<2; ++nt) {
      float f[8];
      #pragma unroll
      for (int j=0;j<8;++j) f[j] = X[idx[nt] + j*HW];
      half2v* bh = (half2v*)&b[nt];
      #pragma unroll
      for (int j=0;j<4;++j) bh[j] = pkrtz(f[2*j], f[2*j+1]);
    }
    #pragma unroll
    for (int mt=0; mt<6; ++mt)
      #pragma unroll
      for (int nt=0; nt<2; ++nt)
        acc[mt][nt] = __builtin_amdgcn_mfma_f32_16x16x32_f16(a[mt], b[nt], acc[mt][nt], 0, 0, 0);
    Ap += 32;
    #pragma unroll
    for (int nt=0; nt<2; ++nt) idx[nt] += 32*HW;
  }

  #pragma unroll
  for (int mt=0; mt<6; ++mt) {
    float4 bv = *(const float4*)(bias + mt*16 + quad*4);
    int co = mt*16 + quad*4;
    int g = co >> 3; int h = co & 7;
    #pragma unroll
    for (int nt=0; nt<2; ++nt) {
      int pos = m0 + wv*32 + nt*16 + mr;
      half4v o;
      o[0] = (_Float16)silu_f(acc[mt][nt][0] + bv.x);
      o[1] = (_Float16)silu_f(acc[mt][nt][1] + bv.y);
      o[2] = (_Float16)silu_f(acc[mt][nt][2] + bv.z);
      o[3] = (_Float16)silu_f(acc[mt][nt][3] + bv.w);
      *(half4v*)(Out + ((long)g*NDW + pos)*8 + h) = o;
    }
  }
}

// ---------------------------------------------------------------------------
// Expand GEMM, both branches: channel-major stemO -> channel-major padded.
// grid (1050, 2, 2). XCD-bijective swizzle on blockIdx.x.
// ---------------------------------------------------------------------------
__global__ __launch_bounds__(256) void expand2_k(
    const _Float16* __restrict__ A, const _Float16* __restrict__ wbf,
    const float* __restrict__ b1c, const float* __restrict__ b1r,
    _Float16* __restrict__ OutBase)
{
  const int bz = blockIdx.z;
  const _Float16* Wb = wbf + 86016 + bz*55296;
  _Float16* Out = OutBase + bz*EXPAD_ELEMS;
  const float* b1 = bz ? b1r : b1c;

  int orig = blockIdx.x;
  int xcd = orig & 7; int loc = orig >> 3;
  int bx = (xcd < 2 ? xcd*132 : 2*132 + (xcd-2)*131) + loc;

  const int m0 = bx << 7;
  const int lvl = (m0 < 102400) ? 0 : (m0 < 128000 ? 1 : 2);
  const int HW  = (lvl==0)?6400:(lvl==1?1600:400);
  const int W   = (lvl==0)?80:(lvl==1?40:20);
  const int noff= (lvl==0)?0:(lvl==1?102400:128000);
  const int PLB = (lvl==0)?0:(lvl==1?107584:135808);
  const int PW  = W + 2;
  const int co0 = blockIdx.y * 96;
  int t = threadIdx.x, lane = t & 63, wv = t >> 6;
  int mr = lane & 15, quad = lane >> 4;
  const _Float16* Ap0 = A + ((long)quad*NDW + (m0 + wv*32 + mr))*8;  // acts, ch-major
  const _Float16* Bp = Wb + ((long)(co0 + mr))*96 + quad*8;          // weights
  const float* bp = b1 + lvl*192 + co0;

  floatx4 zero = {0.f,0.f,0.f,0.f};
  floatx4 acc[6][2];     // [co tile][pos tile]
  #pragma unroll
  for (int i=0;i<6;++i)
    #pragma unroll
    for (int j=0;j<2;++j) acc[i][j] = zero;

  #pragma unroll
  for (int k=0; k<3; ++k) {
    half8 wf[6], af[2];
    #pragma unroll
    for (int mt=0; mt<6; ++mt) wf[mt] = *(const half8*)(Bp + (long)mt*16*96);
    #pragma unroll
    for (int nt=0; nt<2; ++nt)
      af[nt] = *(const half8*)(Ap0 + ((long)k*4*NDW)*8 + nt*16*8);
    #pragma unroll
    for (int mt=0; mt<6; ++mt)
      #pragma unroll
      for (int nt=0; nt<2; ++nt)
        acc[mt][nt] = __builtin_amdgcn_mfma_f32_16x16x32_f16(wf[mt], af[nt], acc[mt][nt], 0, 0, 0);
    Bp += 32;
  }

  long pp2[2];
  #pragma unroll
  for (int nt=0; nt<2; ++nt) {
    int gm = m0 + wv*32 + nt*16 + mr;
    int m = gm - noff; int b_ = m / HW; int rp = m - b_*HW;
    int y = rp / W;  int x = rp - y*W;
    pp2[nt] = PLB + ((long)b_*PW + (y+1))*PW + (x+1);
  }

  #pragma unroll
  for (int mt=0; mt<6; ++mt) {
    float4 bv = *(const float4*)(bp + mt*16 + quad*4);
    int co = co0 + mt*16 + quad*4;
    int g = co >> 3;            // channel group
    int h = (co & 4);           // 0 or 4 within group
    #pragma unroll
    for (int nt=0; nt<2; ++nt) {
      half4v o;
      o[0] = (_Float16)silu_f(acc[mt][nt][0] + bv.x);
      o[1] = (_Float16)silu_f(acc[mt][nt][1] + bv.y);
      o[2] = (_Float16)silu_f(acc[mt][nt][2] + bv.z);
      o[3] = (_Float16)silu_f(acc[mt][nt][3] + bv.w);
      *(half4v*)(Out + ((long)g*PPOS + pp2[nt])*8 + h) = o;
    }
  }
}

// ---------------------------------------------------------------------------
// FUSED dw3x3 + proj + heads (round-11 structure) with:
//  - halo group stride padded 800 -> 816 hw (1632B = 24 banks shift/group):
//    quads land on 4 distinct bank phases -> ~4-way instead of 8-way conflict
//  - ldsP ALIASES halo (barrier after k-loop): LDS 51.7KB -> 39.2KB
//    -> 4 blocks/CU (+33% resident waves)
//  - s_setprio(1) around the fused dw+MFMA compute (T5)
// grid (2100, 2): x in [0,1600) lvl0 tiles, [1600,2000) lvl1, [2000,2100) lvl2.
// ---------------------------------------------------------------------------
#define PSTRIDE 104
#define HS 816                      // halo group stride (halfwords)
__global__ __launch_bounds__(256, 4) void dwprojhead_k(
    const _Float16* __restrict__ exBase, const _Float16* __restrict__ wbf,
    const float* __restrict__ b2_c, const float* __restrict__ b2_r,
    const _Float16* __restrict__ resid,
    const float* __restrict__ hb, const float* __restrict__ rb,
    const float* __restrict__ ob, float* __restrict__ out)
{
  __shared__ _Float16 halo[24*HS];       // [g][100 entries][8ch], 16-entry pad/group
  _Float16* ldsP = halo;                 // ALIAS: proj out [pos][96] after barrier
  const int bz = blockIdx.y;
  const _Float16* ex = exBase + bz*EXPAD_ELEMS;
  const float* b2 = bz ? b2_r : b2_c;

  int orig = blockIdx.x;
  int xcd = orig & 7; int loc = orig >> 3;
  int bx = (xcd < 4 ? xcd*263 : 4*263 + (xcd-4)*262) + loc;

  int lvl, W, HW, noff, a0, PLB;
  int b_ = 0, y0 = 0, x0 = 0, m0 = 0;
  bool tilep;
  if (bx < 1600) {
    tilep = true; lvl = 0; W = 80; HW = 6400; noff = 0;      a0 = 0;    PLB = 0;
    b_ = bx / 100; int tl = bx - b_*100;
    y0 = (tl / 10) * 8; x0 = (tl - (tl/10)*10) * 8;
  } else if (bx < 2000) {
    tilep = true; lvl = 1; W = 40; HW = 1600; noff = 102400; a0 = 6400; PLB = 107584;
    int rel = bx - 1600; b_ = rel / 25; int tl = rel - b_*25;
    y0 = (tl / 5) * 8; x0 = (tl - (tl/5)*5) * 8;
  } else {
    tilep = false; lvl = 2; W = 20; HW = 400; noff = 128000; a0 = 8000; PLB = 135808;
    m0 = 128000 + ((bx - 2000) << 6);
  }
  const int PW = W + 2;

  int t = threadIdx.x, lane = t & 63, wv = t >> 6;
  int mr = lane & 15, quad = lane >> 4;
  const int p = wv*16 + mr;              // this thread's tile-local position

  const _Float16* wT = wbf + OFF_WDT + bz*5184 + lvl*1728;
  const _Float16* bB = wbf + OFF_DWB + bz*576 + lvl*192;
  const _Float16* Ap = wbf + OFF_W2 + bz*55296 + lvl*18432 + ((long)mr)*192 + quad*8;

  // this thread's global position n
  int n;
  if (tilep) n = noff + b_*HW + (y0 + (p>>3))*W + x0 + (p&7);
  else       n = m0 + p;

  floatx4 pacc[6];
  {
    floatx4 zero = {0.f,0.f,0.f,0.f};
    #pragma unroll
    for (int j=0;j<6;++j) pacc[j] = zero;
  }

  half4v rsv[6];   // resid prefetch

  if (tilep) {
    // ---- stage all 24 group halos via async global_load_lds ----
    const long pb00 = (long)PLB + ((long)b_*PW + y0)*PW + x0;  // padded (y0-1,x0-1)
    {
      int e1 = lane;
      int hy1 = e1 / 10, hx1 = e1 - hy1*10;
      long s1 = pb00 + hy1*PW + hx1;
      int e2 = 64 + lane;
      int hy2 = e2 / 10, hx2 = e2 - hy2*10;
      long s2 = pb00 + hy2*PW + hx2;
      #pragma unroll
      for (int j = 0; j < 6; ++j) {
        int g = wv*6 + j;
        gll16(ex + ((long)g*PPOS + s1)*8, halo + g*HS);
        if (lane < 36)
          gll16(ex + ((long)g*PPOS + s2)*8, halo + g*HS + 512);
      }
    }
    // resid prefetch (independent of staging)
    #pragma unroll
    for (int mt=0; mt<6; ++mt) {
      int co = mt*16 + quad*4;
      int g = co >> 3; int h = co & 7;
      rsv[mt] = *(const half4v*)(resid + ((long)g*NDW + n)*8 + h);
    }
    __syncthreads();   // drain global_load_lds + make halo visible

    // ---- fused dw + proj k-loop, taps from LDS ----
    __builtin_amdgcn_s_setprio(1);
    const int ty = p >> 3, tx = p & 7;
    const _Float16* hb0 = halo + (ty*10 + tx)*8;   // entry (ty,tx) base
    for (int k = 0; k < 6; ++k) {
      const int g = 4*k + quad;
      const _Float16* hg = hb0 + g*HS;
      const _Float16* wp = wT + g*8;

      half8 a[9], w[9];
      #pragma unroll
      for (int dy = 0; dy < 3; ++dy)
        #pragma unroll
        for (int dx = 0; dx < 3; ++dx)
          a[dy*3+dx] = *(const half8*)(hg + (dy*10 + dx)*8);
      #pragma unroll
      for (int tap = 0; tap < 9; ++tap)
        w[tap] = *(const half8*)(wp + tap*192);
      half8 bv8 = *(const half8*)(bB + g*8);
      half8 wf[6];
      #pragma unroll
      for (int mt = 0; mt < 6; ++mt)
        wf[mt] = *(const half8*)(Ap + (long)mt*16*192 + k*32);

      half2v ac0 = {bv8[0], bv8[1]};
      half2v ac1 = {bv8[2], bv8[3]};
      half2v ac2 = {bv8[4], bv8[5]};
      half2v ac3 = {bv8[6], bv8[7]};
      #pragma unroll
      for (int tap = 0; tap < 9; ++tap) {
        ac0 += half2v{a[tap][0],a[tap][1]} * half2v{w[tap][0],w[tap][1]};
        ac1 += half2v{a[tap][2],a[tap][3]} * half2v{w[tap][2],w[tap][3]};
        ac2 += half2v{a[tap][4],a[tap][5]} * half2v{w[tap][4],w[tap][5]};
        ac3 += half2v{a[tap][6],a[tap][7]} * half2v{w[tap][6],w[tap][7]};
      }
      half8 af;
      {
        half2v* oh = (half2v*)&af;
        oh[0] = pkrtz(silu_f((float)ac0[0]), silu_f((float)ac0[1]));
        oh[1] = pkrtz(silu_f((float)ac1[0]), silu_f((float)ac1[1]));
        oh[2] = pkrtz(silu_f((float)ac2[0]), silu_f((float)ac2[1]));
        oh[3] = pkrtz(silu_f((float)ac3[0]), silu_f((float)ac3[1]));
      }
      #pragma unroll
      for (int mt = 0; mt < 6; ++mt)
        pacc[mt] = __builtin_amdgcn_mfma_f32_16x16x32_f16(wf[mt], af, pacc[mt], 0, 0, 0);
    }
    __builtin_amdgcn_s_setprio(0);
  } else {
    // ---- lvl2 linear path: direct-global taps, in-register (round 9) ----
    uint32 mm = (uint32)(n - noff);
    uint32 bb = (uint32)(((unsigned long long)mm * 10737419u) >> 32);   // /400
    uint32 rp = mm - bb*400;
    uint32 yy = (rp * 209716u) >> 22;                                   // /20
    uint32 xx = rp - yy*20;
    long pp = (long)PLB + ((long)bb*PW + (yy+1))*PW + (xx+1);

    #pragma unroll
    for (int mt=0; mt<6; ++mt) {
      int co = mt*16 + quad*4;
      int g = co >> 3; int h = co & 7;
      rsv[mt] = *(const half4v*)(resid + ((long)g*NDW + n)*8 + h);
    }

    for (int k = 0; k < 6; ++k) {
      const int g = 4*k + quad;
      const _Float16* exg = ex + ((long)g*PPOS + pp)*8;
      const _Float16* wp = wT + g*8;

      half8 a[9], w[9];
      #pragma unroll
      for (int dy = 0; dy < 3; ++dy)
        #pragma unroll
        for (int dx = 0; dx < 3; ++dx)
          a[dy*3+dx] = *(const half8*)(exg + ((long)(dy-1)*PW + (dx-1))*8);
      #pragma unroll
      for (int tap = 0; tap < 9; ++tap)
        w[tap] = *(const half8*)(wp + tap*192);
      half8 bv8 = *(const half8*)(bB + g*8);
      half8 wf[6];
      #pragma unroll
      for (int mt = 0; mt < 6; ++mt)
        wf[mt] = *(const half8*)(Ap + (long)mt*16*192 + k*32);

      half2v ac0 = {bv8[0], bv8[1]};
      half2v ac1 = {bv8[2], bv8[3]};
      half2v ac2 = {bv8[4], bv8[5]};
      half2v ac3 = {bv8[6], bv8[7]};
      #pragma unroll
      for (int tap = 0; tap < 9; ++tap) {
        ac0 += half2v{a[tap][0],a[tap][1]} * half2v{w[tap][0],w[tap][1]};
        ac1 += half2v{a[tap][2],a[tap][3]} * half2v{w[tap][2],w[tap][3]};
        ac2 += half2v{a[tap][4],a[tap][5]} * half2v{w[tap][4],w[tap][5]};
        ac3 += half2v{a[tap][6],a[tap][7]} * half2v{w[tap][6],w[tap][7]};
      }
      half8 af;
      {
        half2v* oh = (half2v*)&af;
        oh[0] = pkrtz(silu_f((float)ac0[0]), silu_f((float)ac0[1]));
        oh[1] = pkrtz(silu_f((float)ac1[0]), silu_f((float)ac1[1]));
        oh[2] = pkrtz(silu_f((float)ac2[0]), silu_f((float)ac2[1]));
        oh[3] = pkrtz(silu_f((float)ac3[0]), silu_f((float)ac3[1]));
      }
      #pragma unroll
      for (int mt = 0; mt < 6; ++mt)
        pacc[mt] = __builtin_amdgcn_mfma_f32_16x16x32_f16(wf[mt], af, pacc[mt], 0, 0, 0);
    }
  }

  __syncthreads();   // all halo reads done -> safe to overwrite as ldsP

  // ---- epilogue: + bias + prefetched residual -> ldsP [pos][co] ----
  {
    const float* bp2 = b2 + lvl*96;
    #pragma unroll
    for (int mt=0; mt<6; ++mt) {
      int co = mt*16 + quad*4;
      float4 bv = *(const float4*)(bp2 + co);
      half4v o;
      o[0] = (_Float16)(pacc[mt][0] + bv.x + (float)rsv[mt][0]);
      o[1] = (_Float16)(pacc[mt][1] + bv.y + (float)rsv[mt][1]);
      o[2] = (_Float16)(pacc[mt][2] + bv.z + (float)rsv[mt][2]);
      o[3] = (_Float16)(pacc[mt][3] + bv.w + (float)rsv[mt][3]);
      *(half4v*)(ldsP + p*PSTRIDE + co) = o;
    }
  }
  // heads read only this wave's 16 rows -> no barrier (same-wave ds ordering).

  // ---- heads ----
  if (bz == 0) {
    const _Float16* Bp = wbf + OFF_HEAD + lvl*7680 + ((long)mr)*96 + quad*8;
    const float* bp = hb + lvl*80;
    floatx4 zero = {0.f,0.f,0.f,0.f};
    floatx4 acc[5];
    #pragma unroll
    for (int j=0;j<5;++j) acc[j] = zero;

    #pragma unroll
    for (int k=0; k<3; ++k) {
      half8 a = *(const half8*)(ldsP + (wv*16 + mr)*PSTRIDE + k*32 + quad*8);
      half8 b[5];
      #pragma unroll
      for (int nt=0; nt<5; ++nt)
        b[nt] = *(const half8*)(Bp + (long)nt*16*96 + k*32);
      #pragma unroll
      for (int nt=0; nt<5; ++nt)
        acc[nt] = __builtin_amdgcn_mfma_f32_16x16x32_f16(a, b[nt], acc[nt], 0, 0, 0);
    }

    #pragma unroll
    for (int nt=0; nt<5; ++nt) {
      int co = nt*16 + mr;
      float bv = bp[co];
      #pragma unroll
      for (int r=0; r<4; ++r) {
        int pq = wv*16 + quad*4 + r;       // tile-local position
        int rpp, bb;
        if (tilep) { bb = b_; rpp = (y0 + (pq>>3))*W + x0 + (pq&7); }
        else {
          uint32 mm = (uint32)(m0 + pq - noff);
          bb = (int)(((unsigned long long)mm * 10737419u) >> 32);
          rpp = (int)(mm - (uint32)bb*400u);
        }
        out[((long)(bb*8400 + a0 + rpp))*85 + 5 + co] = sigm_f(acc[nt][r] + bv);
      }
    }
  } else {
    const _Float16* Bp = wbf + OFF_ROBJ + lvl*1536 + ((long)mr)*96 + quad*8;
    float bv = (mr < 4) ? rb[lvl*4 + mr] : ((mr == 4) ? ob[lvl] : 0.f);
    float sc = (lvl==0) ? 8.f : (lvl==1 ? 16.f : 32.f);
    floatx4 acc = {0.f,0.f,0.f,0.f};
    #pragma unroll
    for (int k=0; k<3; ++k) {
      half8 a = *(const half8*)(ldsP + (wv*16 + mr)*PSTRIDE + k*32 + quad*8);
      half8 b = *(const half8*)(Bp + k*32);
      acc = __builtin_amdgcn_mfma_f32_16x16x32_f16(a, b, acc, 0, 0, 0);
    }
    #pragma unroll
    for (int r=0; r<4; ++r) {
      int pq = wv*16 + quad*4 + r;
      int bb, rpp, yy, xx;
      if (tilep) {
        bb = b_; yy = y0 + (pq>>3); xx = x0 + (pq&7); rpp = yy*W + xx;
      } else {
        uint32 mm = (uint32)(m0 + pq - noff);
        bb = (int)(((unsigned long long)mm * 10737419u) >> 32);
        rpp = (int)(mm - (uint32)bb*400u);
        yy = (int)(((uint32)rpp * 209716u) >> 22);
        xx = rpp - yy*20;
      }
      float v = acc[r] + bv;
      float o;
      if      (mr == 0) o = (v + (float)xx)*sc;
      else if (mr == 1) o = (v + (float)yy)*sc;
      else if (mr <  4) o = __expf(v)*sc;
      else              o = sigm_f(v);
      if (mr < 5)
        out[((long)(bb*8400 + a0 + rpp))*85 + mr] = o;
    }
  }
}

extern "C" void kernel_launch(void* const* d_in, const int* in_sizes, int n_in,
                              void* d_out, int out_size, void* d_ws, size_t ws_size,
                              hipStream_t stream)
{
  bool dict = (in_sizes[1] == 96*128);
  const float* X[3]; const float* SW[3]; const float* SB[3];
  if (dict) {
    X[0]=(const float*)d_in[0]; SW[0]=(const float*)d_in[1]; SB[0]=(const float*)d_in[2];
    X[1]=(const float*)d_in[3]; SW[1]=(const float*)d_in[4]; SB[1]=(const float*)d_in[5];
    X[2]=(const float*)d_in[6]; SW[2]=(const float*)d_in[7]; SB[2]=(const float*)d_in[8];
  } else {
    X[0]=(const float*)d_in[0]; X[1]=(const float*)d_in[1]; X[2]=(const float*)d_in[2];
    SW[0]=(const float*)d_in[3]; SB[0]=(const float*)d_in[4];
    SW[1]=(const float*)d_in[5]; SB[1]=(const float*)d_in[6];
    SW[2]=(const float*)d_in[7]; SB[2]=(const float*)d_in[8];
  }
  const float* br_w1[2] = {(const float*)d_in[9],  (const float*)d_in[15]};
  const float* br_b1[2] = {(const float*)d_in[10], (const float*)d_in[16]};
  const float* br_wd[2] = {(const float*)d_in[11], (const float*)d_in[17]};
  const float* br_bd[2] = {(const float*)d_in[12], (const float*)d_in[18]};
  const float* br_w2[2] = {(const float*)d_in[13], (const float*)d_in[19]};
  const float* br_b2[2] = {(const float*)d_in[14], (const float*)d_in[20]};
  const float* clsp_w=(const float*)d_in[21]; const float* clsp_b=(const float*)d_in[22];
  const float* regp_w=(const float*)d_in[23]; const float* regp_b=(const float*)d_in[24];
  const float* objp_w=(const float*)d_in[25]; const float* objp_b=(const float*)d_in[26];

  float* out = (float*)d_out;

  _Float16* wbf   = (_Float16*)d_ws;
  _Float16* stemO = wbf + WTOT;
  _Float16* bufA  = stemO + 12902400;

  // 1. weights/bias -> fp16 blob
  wconv_k<<<1353,256,0,stream>>>(SW[0],SW[1],SW[2],br_w1[0],br_w1[1],
                                 br_w2[0],br_w2[1],clsp_w,br_wd[0],br_wd[1],
                                 regp_w,objp_w,br_bd[0],br_bd[1],wbf);

  // 2. zero the padded borders of the expand buffers
  zpad_k<<<1716,256,0,stream>>>(bufA);

  // 3. stem GEMM straight from NCHW fp32, channel-major output
  stem_k<<<1050,256,0,stream>>>(X[0],X[1],X[2],wbf,SB[0],SB[1],SB[2],stemO);

  // 4. expand GEMM, both branches, channel-major padded output
  expand2_k<<<dim3(1050,2,2),256,0,stream>>>(stemO, wbf, br_b1[0], br_b1[1], bufA);

  // 5. FUSED dw3x3 + project + residual + heads (aliased LDS, padded halo)
  dwprojhead_k<<<dim3(2100,2),256,0,stream>>>(
      bufA, wbf, br_b2[0], br_b2[1], stemO,
      clsp_b, regp_b, objp_b, out);
}

// Round 13
// 222.046 us; speedup vs baseline: 1.1546x; 1.1546x over previous
//
#include <hip/hip_runtime.h>

typedef unsigned int uint32;
using half2v  = __attribute__((ext_vector_type(2))) _Float16;
using half4v  = __attribute__((ext_vector_type(4))) _Float16;
using half8   = __attribute__((ext_vector_type(8))) _Float16;
using floatx4 = __attribute__((ext_vector_type(4))) float;

__device__ __forceinline__ float sigm_f(float x){
  return __builtin_amdgcn_rcpf(1.0f + __expf(-x));
}
__device__ __forceinline__ float silu_f(float x){ return x * sigm_f(x); }

__device__ __forceinline__ half2v pkrtz(float a, float b){
  return __builtin_bit_cast(half2v, __builtin_amdgcn_cvt_pkrtz(a, b));
}

// async global->LDS, 16B per lane, zero VGPR cost. dst is wave-uniform base;
// HW writes lane i at dst + i*16B. src is per-lane.
__device__ __forceinline__ void gll16(const _Float16* src, _Float16* ldsDst){
  __builtin_amdgcn_global_load_lds(
      (const __attribute__((address_space(1))) uint32*)src,
      (__attribute__((address_space(3))) uint32*)ldsDst, 16, 0, 0);
}

// ---------------------------------------------------------------------------
// fp16 weight blob layout (element offsets): see previous rounds.
// ---------------------------------------------------------------------------
#define OFF_W2    196608
#define OFF_HEAD  307200
#define OFF_WDT   330240
#define OFF_ROBJ  340608
#define OFF_DWB   345216
#define WTOT      346368

// padded expand buffer, CHANNEL-GROUP-MAJOR: per branch [g=24][pp=143552][8ch]
#define PPOS 143552L
#define EXPAD_ELEMS 27561984L   // 24*143552*8
// stem output, CHANNEL-GROUP-MAJOR: [g=12][n=134400][8ch]
#define NDW  134400L

__global__ __launch_bounds__(256) void wconv_k(
    const float* __restrict__ s0, const float* __restrict__ s1,
    const float* __restrict__ s2, const float* __restrict__ cw1,
    const float* __restrict__ rw1, const float* __restrict__ cw2,
    const float* __restrict__ rw2, const float* __restrict__ chw,
    const float* __restrict__ cwd, const float* __restrict__ rwd,
    const float* __restrict__ rpw, const float* __restrict__ opw,
    const float* __restrict__ cbd, const float* __restrict__ rbd,
    _Float16* __restrict__ dst)
{
  int i = blockIdx.x*256 + threadIdx.x;
  if (i >= WTOT) return;
  float v;
  if (i < OFF_WDT) {
    const float* p; int off;
    if      (i < 12288)  { p = s0;  off = i; }
    else if (i < 36864)  { p = s1;  off = i - 12288; }
    else if (i < 86016)  { p = s2;  off = i - 36864; }
    else if (i < 141312) { p = cw1; off = i - 86016; }
    else if (i < 196608) { p = rw1; off = i - 141312; }
    else if (i < 251904) { p = cw2; off = i - 196608; }
    else if (i < 307200) { p = rw2; off = i - 251904; }
    else                 { p = chw; off = i - 307200; }
    v = p[off];
  } else if (i < OFF_ROBJ) {
    int rel = i - OFF_WDT;
    int br = rel / 5184; int r2 = rel - br*5184;
    int lvl = r2 / 1728; int r3 = r2 - lvl*1728;
    int j = r3 / 192;    int c = r3 - j*192;
    const float* wd = br ? rwd : cwd;
    v = wd[lvl*1728 + c*9 + j];
  } else if (i < OFF_DWB) {
    int rel = i - OFF_ROBJ;
    int lvl = rel / 1536; int r2 = rel - lvl*1536;
    int co = r2 / 96;     int k = r2 - co*96;
    v = (co < 4) ? rpw[lvl*384 + co*96 + k] : (co == 4 ? opw[lvl*96 + k] : 0.f);
  } else {
    int rel = i - OFF_DWB;
    int br = rel / 576;  int r2 = rel - br*576;
    int lvl = r2 / 192;  int c = r2 - lvl*192;
    v = (br ? rbd : cbd)[lvl*192 + c];
  }
  dst[i] = (_Float16)v;
}

// ---------------------------------------------------------------------------
// Zero the 1-pixel border of the padded expand buffers (channel-major).
// ---------------------------------------------------------------------------
__global__ __launch_bounds__(256) void zpad_k(_Float16* __restrict__ exBase)
{
  int ci = blockIdx.x*256 + threadIdx.x;
  if (ci >= 439296) return;
  int br = ci / 219648; int r = ci - br*219648;
  int W, PLB, rem, perimg;
  if (r < 124416)      { W=80; PLB=0;      rem = r;          perimg = 7776; }
  else if (r < 187392) { W=40; PLB=107584; rem = r - 124416; perimg = 3936; }
  else                 { W=20; PLB=135808; rem = r - 187392; perimg = 2016; }
  int b = rem / perimg; int t3 = rem - b*perimg;
  int p = t3 / 24; int g = t3 - p*24;
  int PW = W + 2;
  int row, col;
  if (p < 2*PW) { row = (p >= PW) ? (W+1) : 0; col = (p >= PW) ? (p - PW) : p; }
  else { int q = p - 2*PW; row = 1 + (q >> 1); col = (q & 1) ? (W+1) : 0; }
  long pp = (long)PLB + (long)b*PW*PW + row*PW + col;
  half8 z = {(_Float16)0,(_Float16)0,(_Float16)0,(_Float16)0,
             (_Float16)0,(_Float16)0,(_Float16)0,(_Float16)0};
  *(half8*)(exBase + br*EXPAD_ELEMS + ((long)g*PPOS + pp)*8) = z;
}

// ---------------------------------------------------------------------------
// Stem GEMM from NCHW fp32, fp16 MFMA. Output CHANNEL-GROUP-MAJOR [g][n][8].
// ---------------------------------------------------------------------------
__global__ __launch_bounds__(256) void stem_k(
    const float* __restrict__ x0, const float* __restrict__ x1,
    const float* __restrict__ x2, const _Float16* __restrict__ Wb,
    const float* __restrict__ sb0, const float* __restrict__ sb1,
    const float* __restrict__ sb2, _Float16* __restrict__ Out)
{
  const int m0 = blockIdx.x << 7;
  const int lvl = (m0 < 102400) ? 0 : (m0 < 128000 ? 1 : 2);
  const int CIN = (lvl==0)?128:(lvl==1?256:512);
  const int HW  = (lvl==0)?6400:(lvl==1?1600:400);
  const int noff= (lvl==0)?0:(lvl==1?102400:128000);
  const float* X = (lvl==0)?x0:(lvl==1?x1:x2);
  const _Float16* Wl = Wb + ((lvl==0)?0:(lvl==1?12288:36864));
  const float* bias = (lvl==0)?sb0:(lvl==1?sb1:sb2);

  int t=threadIdx.x, lane=t&63, wv=t>>6, mr=lane&15, quad=lane>>4;

  int idx[2];
  #pragma unroll
  for (int nt=0; nt<2; ++nt) {
    int n = m0 + wv*32 + nt*16 + mr;
    int m = n - noff; int b_ = m / HW; int p = m - b_*HW;
    idx[nt] = (b_*CIN + quad*8)*HW + p;
  }
  const _Float16* Ap = Wl + mr*CIN + quad*8;

  floatx4 zero = {0.f,0.f,0.f,0.f};
  floatx4 acc[6][2];
  #pragma unroll
  for (int i=0;i<6;++i)
    #pragma unroll
    for (int j=0;j<2;++j) acc[i][j] = zero;

  for (int k=0; k<CIN; k+=32) {
    half8 a[6], b[2];
    #pragma unroll
    for (int mt=0; mt<6; ++mt) a[mt] = *(const half8*)(Ap + mt*16*CIN);
    #pragma unroll
    for (int nt=0; nt<2; ++nt) {
      float f[8];
      #pragma unroll
      for (int j=0;j<8;++j) f[j] = X[idx[nt] + j*HW];
      half2v* bh = (half2v*)&b[nt];
      #pragma unroll
      for (int j=0;j<4;++j) bh[j] = pkrtz(f[2*j], f[2*j+1]);
    }
    #pragma unroll
    for (int mt=0; mt<6; ++mt)
      #pragma unroll
      for (int nt=0; nt<2; ++nt)
        acc[mt][nt] = __builtin_amdgcn_mfma_f32_16x16x32_f16(a[mt], b[nt], acc[mt][nt], 0, 0, 0);
    Ap += 32;
    #pragma unroll
    for (int nt=0; nt<2; ++nt) idx[nt] += 32*HW;
  }

  #pragma unroll
  for (int mt=0; mt<6; ++mt) {
    float4 bv = *(const float4*)(bias + mt*16 + quad*4);
    int co = mt*16 + quad*4;
    int g = co >> 3; int h = co & 7;
    #pragma unroll
    for (int nt=0; nt<2; ++nt) {
      int pos = m0 + wv*32 + nt*16 + mr;
      half4v o;
      o[0] = (_Float16)silu_f(acc[mt][nt][0] + bv.x);
      o[1] = (_Float16)silu_f(acc[mt][nt][1] + bv.y);
      o[2] = (_Float16)silu_f(acc[mt][nt][2] + bv.z);
      o[3] = (_Float16)silu_f(acc[mt][nt][3] + bv.w);
      *(half4v*)(Out + ((long)g*NDW + pos)*8 + h) = o;
    }
  }
}

// ---------------------------------------------------------------------------
// Expand GEMM, both branches: channel-major stemO -> channel-major padded.
// grid (1050, 2, 2). XCD-bijective swizzle on blockIdx.x.
// ---------------------------------------------------------------------------
__global__ __launch_bounds__(256) void expand2_k(
    const _Float16* __restrict__ A, const _Float16* __restrict__ wbf,
    const float* __restrict__ b1c, const float* __restrict__ b1r,
    _Float16* __restrict__ OutBase)
{
  const int bz = blockIdx.z;
  const _Float16* Wb = wbf + 86016 + bz*55296;
  _Float16* Out = OutBase + bz*EXPAD_ELEMS;
  const float* b1 = bz ? b1r : b1c;

  int orig = blockIdx.x;
  int xcd = orig & 7; int loc = orig >> 3;
  int bx = (xcd < 2 ? xcd*132 : 2*132 + (xcd-2)*131) + loc;

  const int m0 = bx << 7;
  const int lvl = (m0 < 102400) ? 0 : (m0 < 128000 ? 1 : 2);
  const int HW  = (lvl==0)?6400:(lvl==1?1600:400);
  const int W   = (lvl==0)?80:(lvl==1?40:20);
  const int noff= (lvl==0)?0:(lvl==1?102400:128000);
  const int PLB = (lvl==0)?0:(lvl==1?107584:135808);
  const int PW  = W + 2;
  const int co0 = blockIdx.y * 96;
  int t = threadIdx.x, lane = t & 63, wv = t >> 6;
  int mr = lane & 15, quad = lane >> 4;
  const _Float16* Ap0 = A + ((long)quad*NDW + (m0 + wv*32 + mr))*8;  // acts, ch-major
  const _Float16* Bp = Wb + ((long)(co0 + mr))*96 + quad*8;          // weights
  const float* bp = b1 + lvl*192 + co0;

  floatx4 zero = {0.f,0.f,0.f,0.f};
  floatx4 acc[6][2];     // [co tile][pos tile]
  #pragma unroll
  for (int i=0;i<6;++i)
    #pragma unroll
    for (int j=0;j<2;++j) acc[i][j] = zero;

  #pragma unroll
  for (int k=0; k<3; ++k) {
    half8 wf[6], af[2];
    #pragma unroll
    for (int mt=0; mt<6; ++mt) wf[mt] = *(const half8*)(Bp + (long)mt*16*96);
    #pragma unroll
    for (int nt=0; nt<2; ++nt)
      af[nt] = *(const half8*)(Ap0 + ((long)k*4*NDW)*8 + nt*16*8);
    #pragma unroll
    for (int mt=0; mt<6; ++mt)
      #pragma unroll
      for (int nt=0; nt<2; ++nt)
        acc[mt][nt] = __builtin_amdgcn_mfma_f32_16x16x32_f16(wf[mt], af[nt], acc[mt][nt], 0, 0, 0);
    Bp += 32;
  }

  long pp2[2];
  #pragma unroll
  for (int nt=0; nt<2; ++nt) {
    int gm = m0 + wv*32 + nt*16 + mr;
    int m = gm - noff; int b_ = m / HW; int rp = m - b_*HW;
    int y = rp / W;  int x = rp - y*W;
    pp2[nt] = PLB + ((long)b_*PW + (y+1))*PW + (x+1);
  }

  #pragma unroll
  for (int mt=0; mt<6; ++mt) {
    float4 bv = *(const float4*)(bp + mt*16 + quad*4);
    int co = co0 + mt*16 + quad*4;
    int g = co >> 3;            // channel group
    int h = (co & 4);           // 0 or 4 within group
    #pragma unroll
    for (int nt=0; nt<2; ++nt) {
      half4v o;
      o[0] = (_Float16)silu_f(acc[mt][nt][0] + bv.x);
      o[1] = (_Float16)silu_f(acc[mt][nt][1] + bv.y);
      o[2] = (_Float16)silu_f(acc[mt][nt][2] + bv.z);
      o[3] = (_Float16)silu_f(acc[mt][nt][3] + bv.w);
      *(half4v*)(Out + ((long)g*PPOS + pp2[nt])*8 + h) = o;
    }
  }
}

// ---------------------------------------------------------------------------
// FUSED dw3x3 + proj + heads (round-11 config: 3 blk/CU, separate ldsP,
// no setprio) with ALL levels on the 8x8 tile path:
//   lvl0: 10x10 tiles/img (1600), lvl1: 5x5 (400),
//   lvl2: 3x3 OVERLAPPING tiles/img, y0,x0 in {0,6,12} (144) -- overlapped
//   positions recompute identical values; duplicate out-writes are benign.
// grid (2144, 2), 2144 = 8*268 -> clean XCD-bijective swizzle.
// LDS: halo 24*800*2 = 38.4KB + ldsP 13.3KB = 51.7KB -> 3 blocks/CU
// (4 blocks thrash per-XCD L2: round-12 regression).
// ---------------------------------------------------------------------------
#define PSTRIDE 104
__global__ __launch_bounds__(256, 3) void dwprojhead_k(
    const _Float16* __restrict__ exBase, const _Float16* __restrict__ wbf,
    const float* __restrict__ b2_c, const float* __restrict__ b2_r,
    const _Float16* __restrict__ resid,
    const float* __restrict__ hb, const float* __restrict__ rb,
    const float* __restrict__ ob, float* __restrict__ out)
{
  __shared__ _Float16 halo[24*800];      // [g][100 entries][8ch]
  __shared__ _Float16 ldsP[64*PSTRIDE];  // proj out [pos][96], intra-wave only
  const int bz = blockIdx.y;
  const _Float16* ex = exBase + bz*EXPAD_ELEMS;
  const float* b2 = bz ? b2_r : b2_c;

  int orig = blockIdx.x;
  int bx = (orig & 7)*268 + (orig >> 3);   // bijective: 2144 = 8*268

  int lvl, W, HW, noff, a0, PLB;
  int b_, y0, x0;
  if (bx < 1600) {
    lvl = 0; W = 80; HW = 6400; noff = 0;      a0 = 0;    PLB = 0;
    b_ = bx / 100; int tl = bx - b_*100;
    y0 = (tl / 10) * 8; x0 = (tl - (tl/10)*10) * 8;
  } else if (bx < 2000) {
    lvl = 1; W = 40; HW = 1600; noff = 102400; a0 = 6400; PLB = 107584;
    int rel = bx - 1600; b_ = rel / 25; int tl = rel - b_*25;
    y0 = (tl / 5) * 8; x0 = (tl - (tl/5)*5) * 8;
  } else {
    lvl = 2; W = 20; HW = 400; noff = 128000; a0 = 8000; PLB = 135808;
    int rel = bx - 2000; b_ = rel / 9; int tl = rel - b_*9;
    int iy = tl / 3; int ix = tl - iy*3;
    y0 = iy*6; x0 = ix*6;                 // overlapping 8x8 tiles on 20x20
  }
  const int PW = W + 2;

  int t = threadIdx.x, lane = t & 63, wv = t >> 6;
  int mr = lane & 15, quad = lane >> 4;
  const int p = wv*16 + mr;              // this thread's tile-local position

  const _Float16* wT = wbf + OFF_WDT + bz*5184 + lvl*1728;
  const _Float16* bB = wbf + OFF_DWB + bz*576 + lvl*192;
  const _Float16* Ap = wbf + OFF_W2 + bz*55296 + lvl*18432 + ((long)mr)*192 + quad*8;

  // this thread's global position n
  const int n = noff + b_*HW + (y0 + (p>>3))*W + x0 + (p&7);

  floatx4 pacc[6];
  {
    floatx4 zero = {0.f,0.f,0.f,0.f};
    #pragma unroll
    for (int j=0;j<6;++j) pacc[j] = zero;
  }

  half4v rsv[6];   // resid prefetch

  // ---- stage all 24 group halos via async global_load_lds ----
  const long pb00 = (long)PLB + ((long)b_*PW + y0)*PW + x0;  // padded (y0-1,x0-1)
  {
    int e1 = lane;
    int hy1 = e1 / 10, hx1 = e1 - hy1*10;
    long s1 = pb00 + hy1*PW + hx1;
    int e2 = 64 + lane;
    int hy2 = e2 / 10, hx2 = e2 - hy2*10;
    long s2 = pb00 + hy2*PW + hx2;
    #pragma unroll
    for (int j = 0; j < 6; ++j) {
      int g = wv*6 + j;
      gll16(ex + ((long)g*PPOS + s1)*8, halo + g*800);
      if (lane < 36)
        gll16(ex + ((long)g*PPOS + s2)*8, halo + g*800 + 512);
    }
  }
  // resid prefetch (independent of staging)
  #pragma unroll
  for (int mt=0; mt<6; ++mt) {
    int co = mt*16 + quad*4;
    int g = co >> 3; int h = co & 7;
    rsv[mt] = *(const half4v*)(resid + ((long)g*NDW + n)*8 + h);
  }
  __syncthreads();   // drain global_load_lds + make halo visible

  // ---- fused dw + proj k-loop, taps from LDS ----
  {
    const int ty = p >> 3, tx = p & 7;
    const _Float16* hb0 = halo + (ty*10 + tx)*8;   // entry (ty,tx) base
    for (int k = 0; k < 6; ++k) {
      const int g = 4*k + quad;
      const _Float16* hg = hb0 + g*800;
      const _Float16* wp = wT + g*8;

      half8 a[9], w[9];
      #pragma unroll
      for (int dy = 0; dy < 3; ++dy)
        #pragma unroll
        for (int dx = 0; dx < 3; ++dx)
          a[dy*3+dx] = *(const half8*)(hg + (dy*10 + dx)*8);
      #pragma unroll
      for (int tap = 0; tap < 9; ++tap)
        w[tap] = *(const half8*)(wp + tap*192);
      half8 bv8 = *(const half8*)(bB + g*8);
      half8 wf[6];
      #pragma unroll
      for (int mt = 0; mt < 6; ++mt)
        wf[mt] = *(const half8*)(Ap + (long)mt*16*192 + k*32);

      half2v ac0 = {bv8[0], bv8[1]};
      half2v ac1 = {bv8[2], bv8[3]};
      half2v ac2 = {bv8[4], bv8[5]};
      half2v ac3 = {bv8[6], bv8[7]};
      #pragma unroll
      for (int tap = 0; tap < 9; ++tap) {
        ac0 += half2v{a[tap][0],a[tap][1]} * half2v{w[tap][0],w[tap][1]};
        ac1 += half2v{a[tap][2],a[tap][3]} * half2v{w[tap][2],w[tap][3]};
        ac2 += half2v{a[tap][4],a[tap][5]} * half2v{w[tap][4],w[tap][5]};
        ac3 += half2v{a[tap][6],a[tap][7]} * half2v{w[tap][6],w[tap][7]};
      }
      half8 af;
      {
        half2v* oh = (half2v*)&af;
        oh[0] = pkrtz(silu_f((float)ac0[0]), silu_f((float)ac0[1]));
        oh[1] = pkrtz(silu_f((float)ac1[0]), silu_f((float)ac1[1]));
        oh[2] = pkrtz(silu_f((float)ac2[0]), silu_f((float)ac2[1]));
        oh[3] = pkrtz(silu_f((float)ac3[0]), silu_f((float)ac3[1]));
      }
      #pragma unroll
      for (int mt = 0; mt < 6; ++mt)
        pacc[mt] = __builtin_amdgcn_mfma_f32_16x16x32_f16(wf[mt], af, pacc[mt], 0, 0, 0);
    }
  }

  // ---- epilogue: + bias + prefetched residual -> ldsP [pos][co] ----
  {
    const float* bp2 = b2 + lvl*96;
    #pragma unroll
    for (int mt=0; mt<6; ++mt) {
      int co = mt*16 + quad*4;
      float4 bv = *(const float4*)(bp2 + co);
      half4v o;
      o[0] = (_Float16)(pacc[mt][0] + bv.x + (float)rsv[mt][0]);
      o[1] = (_Float16)(pacc[mt][1] + bv.y + (float)rsv[mt][1]);
      o[2] = (_Float16)(pacc[mt][2] + bv.z + (float)rsv[mt][2]);
      o[3] = (_Float16)(pacc[mt][3] + bv.w + (float)rsv[mt][3]);
      *(half4v*)(ldsP + p*PSTRIDE + co) = o;
    }
  }
  // heads read only this wave's 16 rows -> no barrier (same-wave ds ordering).

  // ---- heads ----
  if (bz == 0) {
    const _Float16* Bp = wbf + OFF_HEAD + lvl*7680 + ((long)mr)*96 + quad*8;
    const float* bp = hb + lvl*80;
    floatx4 zero = {0.f,0.f,0.f,0.f};
    floatx4 acc[5];
    #pragma unroll
    for (int j=0;j<5;++j) acc[j] = zero;

    #pragma unroll
    for (int k=0; k<3; ++k) {
      half8 a = *(const half8*)(ldsP + (wv*16 + mr)*PSTRIDE + k*32 + quad*8);
      half8 b[5];
      #pragma unroll
      for (int nt=0; nt<5; ++nt)
        b[nt] = *(const half8*)(Bp + (long)nt*16*96 + k*32);
      #pragma unroll
      for (int nt=0; nt<5; ++nt)
        acc[nt] = __builtin_amdgcn_mfma_f32_16x16x32_f16(a, b[nt], acc[nt], 0, 0, 0);
    }

    #pragma unroll
    for (int nt=0; nt<5; ++nt) {
      int co = nt*16 + mr;
      float bv = bp[co];
      #pragma unroll
      for (int r=0; r<4; ++r) {
        int pq = wv*16 + quad*4 + r;       // tile-local position
        int rpp = (y0 + (pq>>3))*W + x0 + (pq&7);
        out[((long)(b_*8400 + a0 + rpp))*85 + 5 + co] = sigm_f(acc[nt][r] + bv);
      }
    }
  } else {
    const _Float16* Bp = wbf + OFF_ROBJ + lvl*1536 + ((long)mr)*96 + quad*8;
    float bv = (mr < 4) ? rb[lvl*4 + mr] : ((mr == 4) ? ob[lvl] : 0.f);
    float sc = (lvl==0) ? 8.f : (lvl==1 ? 16.f : 32.f);
    floatx4 acc = {0.f,0.f,0.f,0.f};
    #pragma unroll
    for (int k=0; k<3; ++k) {
      half8 a = *(const half8*)(ldsP + (wv*16 + mr)*PSTRIDE + k*32 + quad*8);
      half8 b = *(const half8*)(Bp + k*32);
      acc = __builtin_amdgcn_mfma_f32_16x16x32_f16(a, b, acc, 0, 0, 0);
    }
    #pragma unroll
    for (int r=0; r<4; ++r) {
      int pq = wv*16 + quad*4 + r;
      int yy = y0 + (pq>>3); int xx = x0 + (pq&7);
      int rpp = yy*W + xx;
      float v = acc[r] + bv;
      float o;
      if      (mr == 0) o = (v + (float)xx)*sc;
      else if (mr == 1) o = (v + (float)yy)*sc;
      else if (mr <  4) o = __expf(v)*sc;
      else              o = sigm_f(v);
      if (mr < 5)
        out[((long)(b_*8400 + a0 + rpp))*85 + mr] = o;
    }
  }
}

extern "C" void kernel_launch(void* const* d_in, const int* in_sizes, int n_in,
                              void* d_out, int out_size, void* d_ws, size_t ws_size,
                              hipStream_t stream)
{
  bool dict = (in_sizes[1] == 96*128);
  const float* X[3]; const float* SW[3]; const float* SB[3];
  if (dict) {
    X[0]=(const float*)d_in[0]; SW[0]=(const float*)d_in[1]; SB[0]=(const float*)d_in[2];
    X[1]=(const float*)d_in[3]; SW[1]=(const float*)d_in[4]; SB[1]=(const float*)d_in[5];
    X[2]=(const float*)d_in[6]; SW[2]=(const float*)d_in[7]; SB[2]=(const float*)d_in[8];
  } else {
    X[0]=(const float*)d_in[0]; X[1]=(const float*)d_in[1]; X[2]=(const float*)d_in[2];
    SW[0]=(const float*)d_in[3]; SB[0]=(const float*)d_in[4];
    SW[1]=(const float*)d_in[5]; SB[1]=(const float*)d_in[6];
    SW[2]=(const float*)d_in[7]; SB[2]=(const float*)d_in[8];
  }
  const float* br_w1[2] = {(const float*)d_in[9],  (const float*)d_in[15]};
  const float* br_b1[2] = {(const float*)d_in[10], (const float*)d_in[16]};
  const float* br_wd[2] = {(const float*)d_in[11], (const float*)d_in[17]};
  const float* br_bd[2] = {(const float*)d_in[12], (const float*)d_in[18]};
  const float* br_w2[2] = {(const float*)d_in[13], (const float*)d_in[19]};
  const float* br_b2[2] = {(const float*)d_in[14], (const float*)d_in[20]};
  const float* clsp_w=(const float*)d_in[21]; const float* clsp_b=(const float*)d_in[22];
  const float* regp_w=(const float*)d_in[23]; const float* regp_b=(const float*)d_in[24];
  const float* objp_w=(const float*)d_in[25]; const float* objp_b=(const float*)d_in[26];

  float* out = (float*)d_out;

  _Float16* wbf   = (_Float16*)d_ws;
  _Float16* stemO = wbf + WTOT;
  _Float16* bufA  = stemO + 12902400;

  // 1. weights/bias -> fp16 blob
  wconv_k<<<1353,256,0,stream>>>(SW[0],SW[1],SW[2],br_w1[0],br_w1[1],
                                 br_w2[0],br_w2[1],clsp_w,br_wd[0],br_wd[1],
                                 regp_w,objp_w,br_bd[0],br_bd[1],wbf);

  // 2. zero the padded borders of the expand buffers
  zpad_k<<<1716,256,0,stream>>>(bufA);

  // 3. stem GEMM straight from NCHW fp32, channel-major output
  stem_k<<<1050,256,0,stream>>>(X[0],X[1],X[2],wbf,SB[0],SB[1],SB[2],stemO);

  // 4. expand GEMM, both branches, channel-major padded output
  expand2_k<<<dim3(1050,2,2),256,0,stream>>>(stemO, wbf, br_b1[0], br_b1[1], bufA);

  // 5. FUSED dw3x3 + project + residual + heads (all-tile path, r11 config)
  dwprojhead_k<<<dim3(2144,2),256,0,stream>>>(
      bufA, wbf, br_b2[0], br_b2[1], stemO,
      clsp_b, regp_b, objp_b, out);
}

// Round 14
// 216.690 us; speedup vs baseline: 1.1831x; 1.0247x over previous
//
#include <hip/hip_runtime.h>

typedef unsigned int uint32;
using half2v  = __attribute__((ext_vector_type(2))) _Float16;
using half4v  = __attribute__((ext_vector_type(4))) _Float16;
using half8   = __attribute__((ext_vector_type(8))) _Float16;
using floatx4 = __attribute__((ext_vector_type(4))) float;

__device__ __forceinline__ float sigm_f(float x){
  return __builtin_amdgcn_rcpf(1.0f + __expf(-x));
}
__device__ __forceinline__ float silu_f(float x){ return x * sigm_f(x); }

__device__ __forceinline__ half2v pkrtz(float a, float b){
  return __builtin_bit_cast(half2v, __builtin_amdgcn_cvt_pkrtz(a, b));
}

// async global->LDS, 16B per lane, zero VGPR cost. dst is wave-uniform base;
// HW writes lane i at dst + i*16B. src is per-lane.
__device__ __forceinline__ void gll16(const _Float16* src, _Float16* ldsDst){
  __builtin_amdgcn_global_load_lds(
      (const __attribute__((address_space(1))) uint32*)src,
      (__attribute__((address_space(3))) uint32*)ldsDst, 16, 0, 0);
}

// ---------------------------------------------------------------------------
// fp16 weight blob layout (element offsets):
//   0      stemW0..2 | 86016 w1 (cls/reg) | 196608 w2 | 307200 clsp_w
//   330240 wdT | 340608 regobj | 345216 dwbias | 346368 total
// ---------------------------------------------------------------------------
#define OFF_W1    86016
#define OFF_W2    196608
#define OFF_HEAD  307200
#define OFF_WDT   330240
#define OFF_ROBJ  340608
#define OFF_DWB   345216
#define WTOT      346368

// stem output, CHANNEL-GROUP-MAJOR: [g=12][n=134400][8ch]
#define NDW  134400L

__global__ __launch_bounds__(256) void wconv_k(
    const float* __restrict__ s0, const float* __restrict__ s1,
    const float* __restrict__ s2, const float* __restrict__ cw1,
    const float* __restrict__ rw1, const float* __restrict__ cw2,
    const float* __restrict__ rw2, const float* __restrict__ chw,
    const float* __restrict__ cwd, const float* __restrict__ rwd,
    const float* __restrict__ rpw, const float* __restrict__ opw,
    const float* __restrict__ cbd, const float* __restrict__ rbd,
    _Float16* __restrict__ dst)
{
  int i = blockIdx.x*256 + threadIdx.x;
  if (i >= WTOT) return;
  float v;
  if (i < OFF_WDT) {
    const float* p; int off;
    if      (i < 12288)  { p = s0;  off = i; }
    else if (i < 36864)  { p = s1;  off = i - 12288; }
    else if (i < 86016)  { p = s2;  off = i - 36864; }
    else if (i < 141312) { p = cw1; off = i - 86016; }
    else if (i < 196608) { p = rw1; off = i - 141312; }
    else if (i < 251904) { p = cw2; off = i - 196608; }
    else if (i < 307200) { p = rw2; off = i - 251904; }
    else                 { p = chw; off = i - 307200; }
    v = p[off];
  } else if (i < OFF_ROBJ) {
    int rel = i - OFF_WDT;
    int br = rel / 5184; int r2 = rel - br*5184;
    int lvl = r2 / 1728; int r3 = r2 - lvl*1728;
    int j = r3 / 192;    int c = r3 - j*192;
    const float* wd = br ? rwd : cwd;
    v = wd[lvl*1728 + c*9 + j];
  } else if (i < OFF_DWB) {
    int rel = i - OFF_ROBJ;
    int lvl = rel / 1536; int r2 = rel - lvl*1536;
    int co = r2 / 96;     int k = r2 - co*96;
    v = (co < 4) ? rpw[lvl*384 + co*96 + k] : (co == 4 ? opw[lvl*96 + k] : 0.f);
  } else {
    int rel = i - OFF_DWB;
    int br = rel / 576;  int r2 = rel - br*576;
    int lvl = r2 / 192;  int c = r2 - lvl*192;
    v = (br ? rbd : cbd)[lvl*192 + c];
  }
  dst[i] = (_Float16)v;
}

// ---------------------------------------------------------------------------
// Stem GEMM from NCHW fp32, fp16 MFMA. Output CHANNEL-GROUP-MAJOR [g][n][8].
// ---------------------------------------------------------------------------
__global__ __launch_bounds__(256) void stem_k(
    const float* __restrict__ x0, const float* __restrict__ x1,
    const float* __restrict__ x2, const _Float16* __restrict__ Wb,
    const float* __restrict__ sb0, const float* __restrict__ sb1,
    const float* __restrict__ sb2, _Float16* __restrict__ Out)
{
  const int m0 = blockIdx.x << 7;
  const int lvl = (m0 < 102400) ? 0 : (m0 < 128000 ? 1 : 2);
  const int CIN = (lvl==0)?128:(lvl==1?256:512);
  const int HW  = (lvl==0)?6400:(lvl==1?1600:400);
  const int noff= (lvl==0)?0:(lvl==1?102400:128000);
  const float* X = (lvl==0)?x0:(lvl==1?x1:x2);
  const _Float16* Wl = Wb + ((lvl==0)?0:(lvl==1?12288:36864));
  const float* bias = (lvl==0)?sb0:(lvl==1?sb1:sb2);

  int t=threadIdx.x, lane=t&63, wv=t>>6, mr=lane&15, quad=lane>>4;

  int idx[2];
  #pragma unroll
  for (int nt=0; nt<2; ++nt) {
    int n = m0 + wv*32 + nt*16 + mr;
    int m = n - noff; int b_ = m / HW; int p = m - b_*HW;
    idx[nt] = (b_*CIN + quad*8)*HW + p;
  }
  const _Float16* Ap = Wl + mr*CIN + quad*8;

  floatx4 zero = {0.f,0.f,0.f,0.f};
  floatx4 acc[6][2];
  #pragma unroll
  for (int i=0;i<6;++i)
    #pragma unroll
    for (int j=0;j<2;++j) acc[i][j] = zero;

  for (int k=0; k<CIN; k+=32) {
    half8 a[6], b[2];
    #pragma unroll
    for (int mt=0; mt<6; ++mt) a[mt] = *(const half8*)(Ap + mt*16*CIN);
    #pragma unroll
    for (int nt=0; nt<2; ++nt) {
      float f[8];
      #pragma unroll
      for (int j=0;j<8;++j) f[j] = X[idx[nt] + j*HW];
      half2v* bh = (half2v*)&b[nt];
      #pragma unroll
      for (int j=0;j<4;++j) bh[j] = pkrtz(f[2*j], f[2*j+1]);
    }
    #pragma unroll
    for (int mt=0; mt<6; ++mt)
      #pragma unroll
      for (int nt=0; nt<2; ++nt)
        acc[mt][nt] = __builtin_amdgcn_mfma_f32_16x16x32_f16(a[mt], b[nt], acc[mt][nt], 0, 0, 0);
    Ap += 32;
    #pragma unroll
    for (int nt=0; nt<2; ++nt) idx[nt] += 32*HW;
  }

  #pragma unroll
  for (int mt=0; mt<6; ++mt) {
    float4 bv = *(const float4*)(bias + mt*16 + quad*4);
    int co = mt*16 + quad*4;
    int g = co >> 3; int h = co & 7;
    #pragma unroll
    for (int nt=0; nt<2; ++nt) {
      int pos = m0 + wv*32 + nt*16 + mr;
      half4v o;
      o[0] = (_Float16)silu_f(acc[mt][nt][0] + bv.x);
      o[1] = (_Float16)silu_f(acc[mt][nt][1] + bv.y);
      o[2] = (_Float16)silu_f(acc[mt][nt][2] + bv.z);
      o[3] = (_Float16)silu_f(acc[mt][nt][3] + bv.w);
      *(half4v*)(Out + ((long)g*NDW + pos)*8 + h) = o;
    }
  }
}

// ---------------------------------------------------------------------------
// MEGAFUSED: expand GEMM + dw3x3 + proj GEMM + residual + heads, per 8x8 tile.
//  1. stage stem 10x10 halo (12 groups, gll16, OOB sources clamped)
//  2. expand GEMM in-block: A=W1 rows (hoisted to regs), B=stem LDS;
//     epilogue writes silu(+bias) -> halo LDS, 0 for out-of-image entries
//     (replaces expand2_k + zpad_k + the padded global buffer)
//  3. dw+proj k-loop (r13, taps from halo, dw frag in-register -> MFMA B)
//  4. epilogue + heads (r13)
// LDS: stemT 12*800 + halo 24*800 = 57.6KB -> 2 blocks/CU; ldsP aliases stemT.
// grid (2144, 2): [0,1600) lvl0, [1600,2000) lvl1, [2000,2144) lvl2
// (overlapping 8x8 tiles on 20x20, y0,x0 in {0,6,12}; dup writes identical).
// ---------------------------------------------------------------------------
#define PSTRIDE 104
__global__ __launch_bounds__(256) void xfuse_k(
    const _Float16* __restrict__ stemO, const _Float16* __restrict__ wbf,
    const float* __restrict__ b1c, const float* __restrict__ b1r,
    const float* __restrict__ b2_c, const float* __restrict__ b2_r,
    const float* __restrict__ hb, const float* __restrict__ rb,
    const float* __restrict__ ob, float* __restrict__ out)
{
  __shared__ _Float16 smem[28800];       // stemT [12][800] | halo [24][800]
  _Float16* stemT = smem;
  _Float16* halo  = smem + 9600;
  _Float16* ldsP  = smem;                // alias: stemT dead after expand phase
  const int bz = blockIdx.y;
  const float* b2 = bz ? b2_r : b2_c;

  int orig = blockIdx.x;
  int bx = (orig & 7)*268 + (orig >> 3);   // bijective: 2144 = 8*268

  int lvl, W, HW, noff, a0;
  int b_, y0, x0;
  if (bx < 1600) {
    lvl = 0; W = 80; HW = 6400; noff = 0;      a0 = 0;
    b_ = bx / 100; int tl = bx - b_*100;
    y0 = (tl / 10) * 8; x0 = (tl - (tl/10)*10) * 8;
  } else if (bx < 2000) {
    lvl = 1; W = 40; HW = 1600; noff = 102400; a0 = 6400;
    int rel = bx - 1600; b_ = rel / 25; int tl = rel - b_*25;
    y0 = (tl / 5) * 8; x0 = (tl - (tl/5)*5) * 8;
  } else {
    lvl = 2; W = 20; HW = 400; noff = 128000; a0 = 8000;
    int rel = bx - 2000; b_ = rel / 9; int tl = rel - b_*9;
    int iy = tl / 3; int ix = tl - iy*3;
    y0 = iy*6; x0 = ix*6;                 // overlapping 8x8 tiles on 20x20
  }

  int t = threadIdx.x, lane = t & 63, wv = t >> 6;
  int mr = lane & 15, quad = lane >> 4;
  const int p = wv*16 + mr;              // this thread's tile-local position

  const _Float16* wT = wbf + OFF_WDT + bz*5184 + lvl*1728;
  const _Float16* bB = wbf + OFF_DWB + bz*576 + lvl*192;
  const _Float16* Ap = wbf + OFF_W2 + bz*55296 + lvl*18432 + ((long)mr)*192 + quad*8;

  // this thread's global position n (center tile)
  const int n = noff + b_*HW + (y0 + (p>>3))*W + x0 + (p&7);

  // ---- 1. stage stem halo (12 groups) via async global_load_lds ----
  {
    // entry -> clamped global position
    int e1 = lane;
    int hy1 = e1 / 10, hx1 = e1 - hy1*10;
    int yy1 = y0 - 1 + hy1; yy1 = yy1 < 0 ? 0 : (yy1 >= W ? W-1 : yy1);
    int xx1 = x0 - 1 + hx1; xx1 = xx1 < 0 ? 0 : (xx1 >= W ? W-1 : xx1);
    long n1 = (long)noff + (long)b_*HW + yy1*W + xx1;
    int e2 = 64 + lane;
    int hy2 = e2 / 10, hx2 = e2 - hy2*10;
    int yy2 = y0 - 1 + hy2; yy2 = yy2 < 0 ? 0 : (yy2 >= W ? W-1 : yy2);
    int xx2 = x0 - 1 + hx2; xx2 = xx2 < 0 ? 0 : (xx2 >= W ? W-1 : xx2);
    long n2 = (long)noff + (long)b_*HW + yy2*W + xx2;
    #pragma unroll
    for (int j = 0; j < 3; ++j) {
      int g = wv*3 + j;
      gll16(stemO + ((long)g*NDW + n1)*8, stemT + g*800);
      if (lane < 36)
        gll16(stemO + ((long)g*NDW + n2)*8, stemT + g*800 + 512);
    }
  }

  // resid prefetch (global; independent of staging)
  half4v rsv[6];
  #pragma unroll
  for (int mt=0; mt<6; ++mt) {
    int co = mt*16 + quad*4;
    int g = co >> 3; int h = co & 7;
    rsv[mt] = *(const half4v*)(stemO + ((long)g*NDW + n)*8 + h);
  }
  __syncthreads();   // drain global_load_lds; stemT visible

  // ---- 2. expand GEMM: W1[48co/wave][96] x stemT[100e][96] -> halo ----
  {
    const _Float16* W1 = wbf + OFF_W1 + bz*55296 + lvl*18432;
    const float* bp1 = (bz ? b1r : b1c) + lvl*192;
    // hoist A-frags: 3 M-tiles x 3 k-steps
    half8 wf[3][3];
    #pragma unroll
    for (int m3 = 0; m3 < 3; ++m3)
      #pragma unroll
      for (int ks = 0; ks < 3; ++ks)
        wf[m3][ks] = *(const half8*)(W1 + (long)((wv*3+m3)*16 + mr)*96 + ks*32 + quad*8);

    #pragma unroll
    for (int nt = 0; nt < 7; ++nt) {
      int ee = nt*16 + mr;
      int e = ee < 100 ? ee : 99;
      floatx4 acc[3];
      #pragma unroll
      for (int m3 = 0; m3 < 3; ++m3) acc[m3] = floatx4{0.f,0.f,0.f,0.f};
      #pragma unroll
      for (int ks = 0; ks < 3; ++ks) {
        half8 af = *(const half8*)(stemT + (ks*4+quad)*800 + e*8);
        #pragma unroll
        for (int m3 = 0; m3 < 3; ++m3)
          acc[m3] = __builtin_amdgcn_mfma_f32_16x16x32_f16(wf[m3][ks], af, acc[m3], 0, 0, 0);
      }
      if (ee < 100) {
        int hy = ee / 10, hx = ee - hy*10;
        int yy = y0 - 1 + hy, xx = x0 - 1 + hx;
        bool oob = ((unsigned)yy >= (unsigned)W) || ((unsigned)xx >= (unsigned)W);
        #pragma unroll
        for (int m3 = 0; m3 < 3; ++m3) {
          int co = (wv*3+m3)*16 + quad*4;
          float4 bv = *(const float4*)(bp1 + co);
          half4v o;
          if (oob) {
            o[0]=o[1]=o[2]=o[3]=(_Float16)0.f;
          } else {
            o[0] = (_Float16)silu_f(acc[m3][0] + bv.x);
            o[1] = (_Float16)silu_f(acc[m3][1] + bv.y);
            o[2] = (_Float16)silu_f(acc[m3][2] + bv.z);
            o[3] = (_Float16)silu_f(acc[m3][3] + bv.w);
          }
          *(half4v*)(halo + (co>>3)*800 + ee*8 + (co&7)) = o;
        }
      }
    }
  }
  __syncthreads();   // halo complete; stemT dead (ldsP may alias)

  // ---- 3. fused dw + proj k-loop, taps from halo LDS ----
  floatx4 pacc[6];
  #pragma unroll
  for (int j=0;j<6;++j) pacc[j] = floatx4{0.f,0.f,0.f,0.f};
  {
    const int ty = p >> 3, tx = p & 7;
    const _Float16* hb0 = halo + (ty*10 + tx)*8;   // entry (ty,tx) base
    for (int k = 0; k < 6; ++k) {
      const int g = 4*k + quad;
      const _Float16* hg = hb0 + g*800;
      const _Float16* wp = wT + g*8;

      half8 a[9], w[9];
      #pragma unroll
      for (int dy = 0; dy < 3; ++dy)
        #pragma unroll
        for (int dx = 0; dx < 3; ++dx)
          a[dy*3+dx] = *(const half8*)(hg + (dy*10 + dx)*8);
      #pragma unroll
      for (int tap = 0; tap < 9; ++tap)
        w[tap] = *(const half8*)(wp + tap*192);
      half8 bv8 = *(const half8*)(bB + g*8);
      half8 wfp[6];
      #pragma unroll
      for (int mt = 0; mt < 6; ++mt)
        wfp[mt] = *(const half8*)(Ap + (long)mt*16*192 + k*32);

      half2v ac0 = {bv8[0], bv8[1]};
      half2v ac1 = {bv8[2], bv8[3]};
      half2v ac2 = {bv8[4], bv8[5]};
      half2v ac3 = {bv8[6], bv8[7]};
      #pragma unroll
      for (int tap = 0; tap < 9; ++tap) {
        ac0 += half2v{a[tap][0],a[tap][1]} * half2v{w[tap][0],w[tap][1]};
        ac1 += half2v{a[tap][2],a[tap][3]} * half2v{w[tap][2],w[tap][3]};
        ac2 += half2v{a[tap][4],a[tap][5]} * half2v{w[tap][4],w[tap][5]};
        ac3 += half2v{a[tap][6],a[tap][7]} * half2v{w[tap][6],w[tap][7]};
      }
      half8 af;
      {
        half2v* oh = (half2v*)&af;
        oh[0] = pkrtz(silu_f((float)ac0[0]), silu_f((float)ac0[1]));
        oh[1] = pkrtz(silu_f((float)ac1[0]), silu_f((float)ac1[1]));
        oh[2] = pkrtz(silu_f((float)ac2[0]), silu_f((float)ac2[1]));
        oh[3] = pkrtz(silu_f((float)ac3[0]), silu_f((float)ac3[1]));
      }
      #pragma unroll
      for (int mt = 0; mt < 6; ++mt)
        pacc[mt] = __builtin_amdgcn_mfma_f32_16x16x32_f16(wfp[mt], af, pacc[mt], 0, 0, 0);
    }
  }

  // ---- 4. epilogue: + bias + prefetched residual -> ldsP [pos][co] ----
  {
    const float* bp2 = b2 + lvl*96;
    #pragma unroll
    for (int mt=0; mt<6; ++mt) {
      int co = mt*16 + quad*4;
      float4 bv = *(const float4*)(bp2 + co);
      half4v o;
      o[0] = (_Float16)(pacc[mt][0] + bv.x + (float)rsv[mt][0]);
      o[1] = (_Float16)(pacc[mt][1] + bv.y + (float)rsv[mt][1]);
      o[2] = (_Float16)(pacc[mt][2] + bv.z + (float)rsv[mt][2]);
      o[3] = (_Float16)(pacc[mt][3] + bv.w + (float)rsv[mt][3]);
      *(half4v*)(ldsP + p*PSTRIDE + co) = o;
    }
  }
  // heads read only this wave's 16 rows -> no barrier (same-wave ds ordering).

  // ---- heads ----
  if (bz == 0) {
    const _Float16* Bp = wbf + OFF_HEAD + lvl*7680 + ((long)mr)*96 + quad*8;
    const float* bp = hb + lvl*80;
    floatx4 acc[5];
    #pragma unroll
    for (int j=0;j<5;++j) acc[j] = floatx4{0.f,0.f,0.f,0.f};

    #pragma unroll
    for (int k=0; k<3; ++k) {
      half8 a = *(const half8*)(ldsP + (wv*16 + mr)*PSTRIDE + k*32 + quad*8);
      half8 b[5];
      #pragma unroll
      for (int nt=0; nt<5; ++nt)
        b[nt] = *(const half8*)(Bp + (long)nt*16*96 + k*32);
      #pragma unroll
      for (int nt=0; nt<5; ++nt)
        acc[nt] = __builtin_amdgcn_mfma_f32_16x16x32_f16(a, b[nt], acc[nt], 0, 0, 0);
    }

    #pragma unroll
    for (int nt=0; nt<5; ++nt) {
      int co = nt*16 + mr;
      float bv = bp[co];
      #pragma unroll
      for (int r=0; r<4; ++r) {
        int pq = wv*16 + quad*4 + r;       // tile-local position
        int rpp = (y0 + (pq>>3))*W + x0 + (pq&7);
        out[((long)(b_*8400 + a0 + rpp))*85 + 5 + co] = sigm_f(acc[nt][r] + bv);
      }
    }
  } else {
    const _Float16* Bp = wbf + OFF_ROBJ + lvl*1536 + ((long)mr)*96 + quad*8;
    float bv = (mr < 4) ? rb[lvl*4 + mr] : ((mr == 4) ? ob[lvl] : 0.f);
    float sc = (lvl==0) ? 8.f : (lvl==1 ? 16.f : 32.f);
    floatx4 acc = {0.f,0.f,0.f,0.f};
    #pragma unroll
    for (int k=0; k<3; ++k) {
      half8 a = *(const half8*)(ldsP + (wv*16 + mr)*PSTRIDE + k*32 + quad*8);
      half8 b = *(const half8*)(Bp + k*32);
      acc = __builtin_amdgcn_mfma_f32_16x16x32_f16(a, b, acc, 0, 0, 0);
    }
    #pragma unroll
    for (int r=0; r<4; ++r) {
      int pq = wv*16 + quad*4 + r;
      int yy = y0 + (pq>>3); int xx = x0 + (pq&7);
      int rpp = yy*W + xx;
      float v = acc[r] + bv;
      float o;
      if      (mr == 0) o = (v + (float)xx)*sc;
      else if (mr == 1) o = (v + (float)yy)*sc;
      else if (mr <  4) o = __expf(v)*sc;
      else              o = sigm_f(v);
      if (mr < 5)
        out[((long)(b_*8400 + a0 + rpp))*85 + mr] = o;
    }
  }
}

extern "C" void kernel_launch(void* const* d_in, const int* in_sizes, int n_in,
                              void* d_out, int out_size, void* d_ws, size_t ws_size,
                              hipStream_t stream)
{
  bool dict = (in_sizes[1] == 96*128);
  const float* X[3]; const float* SW[3]; const float* SB[3];
  if (dict) {
    X[0]=(const float*)d_in[0]; SW[0]=(const float*)d_in[1]; SB[0]=(const float*)d_in[2];
    X[1]=(const float*)d_in[3]; SW[1]=(const float*)d_in[4]; SB[1]=(const float*)d_in[5];
    X[2]=(const float*)d_in[6]; SW[2]=(const float*)d_in[7]; SB[2]=(const float*)d_in[8];
  } else {
    X[0]=(const float*)d_in[0]; X[1]=(const float*)d_in[1]; X[2]=(const float*)d_in[2];
    SW[0]=(const float*)d_in[3]; SB[0]=(const float*)d_in[4];
    SW[1]=(const float*)d_in[5]; SB[1]=(const float*)d_in[6];
    SW[2]=(const float*)d_in[7]; SB[2]=(const float*)d_in[8];
  }
  const float* br_w1[2] = {(const float*)d_in[9],  (const float*)d_in[15]};
  const float* br_b1[2] = {(const float*)d_in[10], (const float*)d_in[16]};
  const float* br_wd[2] = {(const float*)d_in[11], (const float*)d_in[17]};
  const float* br_bd[2] = {(const float*)d_in[12], (const float*)d_in[18]};
  const float* br_w2[2] = {(const float*)d_in[13], (const float*)d_in[19]};
  const float* br_b2[2] = {(const float*)d_in[14], (const float*)d_in[20]};
  const float* clsp_w=(const float*)d_in[21]; const float* clsp_b=(const float*)d_in[22];
  const float* regp_w=(const float*)d_in[23]; const float* regp_b=(const float*)d_in[24];
  const float* objp_w=(const float*)d_in[25]; const float* objp_b=(const float*)d_in[26];

  float* out = (float*)d_out;

  // workspace (fp16 units): wbf 346,368 + stemO 12,902,400 = 26.5 MB
  _Float16* wbf   = (_Float16*)d_ws;
  _Float16* stemO = wbf + WTOT;

  // 1. weights/bias -> fp16 blob
  wconv_k<<<1353,256,0,stream>>>(SW[0],SW[1],SW[2],br_w1[0],br_w1[1],
                                 br_w2[0],br_w2[1],clsp_w,br_wd[0],br_wd[1],
                                 regp_w,objp_w,br_bd[0],br_bd[1],wbf);

  // 2. stem GEMM straight from NCHW fp32, channel-major output
  stem_k<<<1050,256,0,stream>>>(X[0],X[1],X[2],wbf,SB[0],SB[1],SB[2],stemO);

  // 3. MEGAFUSED expand + dw3x3 + project + residual + heads
  xfuse_k<<<dim3(2144,2),256,0,stream>>>(
      stemO, wbf, br_b1[0], br_b1[1], br_b2[0], br_b2[1],
      clsp_b, regp_b, objp_b, out);
}

// Round 15
// 211.015 us; speedup vs baseline: 1.2150x; 1.0269x over previous
//
#include <hip/hip_runtime.h>

typedef unsigned int uint32;
using half2v  = __attribute__((ext_vector_type(2))) _Float16;
using half4v  = __attribute__((ext_vector_type(4))) _Float16;
using half8   = __attribute__((ext_vector_type(8))) _Float16;
using floatx4 = __attribute__((ext_vector_type(4))) float;

__device__ __forceinline__ float sigm_f(float x){
  return __builtin_amdgcn_rcpf(1.0f + __expf(-x));
}
__device__ __forceinline__ float silu_f(float x){ return x * sigm_f(x); }

__device__ __forceinline__ half2v pkrtz(float a, float b){
  return __builtin_bit_cast(half2v, __builtin_amdgcn_cvt_pkrtz(a, b));
}

// ---------------------------------------------------------------------------
// fp16 weight blob layout (element offsets):
//   0      stemW0..2 | 86016 w1 (cls/reg) | 196608 w2 | 307200 clsp_w
//   330240 wdT | 340608 regobj | 345216 dwbias | 346368 total
// ---------------------------------------------------------------------------
#define OFF_W1    86016
#define OFF_W2    196608
#define OFF_HEAD  307200
#define OFF_WDT   330240
#define OFF_ROBJ  340608
#define OFF_DWB   345216
#define WTOT      346368

// stem output, CHANNEL-GROUP-MAJOR: [g=12][n=134400][8ch]
#define NDW  134400L

__global__ __launch_bounds__(256) void wconv_k(
    const float* __restrict__ s0, const float* __restrict__ s1,
    const float* __restrict__ s2, const float* __restrict__ cw1,
    const float* __restrict__ rw1, const float* __restrict__ cw2,
    const float* __restrict__ rw2, const float* __restrict__ chw,
    const float* __restrict__ cwd, const float* __restrict__ rwd,
    const float* __restrict__ rpw, const float* __restrict__ opw,
    const float* __restrict__ cbd, const float* __restrict__ rbd,
    _Float16* __restrict__ dst)
{
  int i = blockIdx.x*256 + threadIdx.x;
  if (i >= WTOT) return;
  float v;
  if (i < OFF_WDT) {
    const float* p; int off;
    if      (i < 12288)  { p = s0;  off = i; }
    else if (i < 36864)  { p = s1;  off = i - 12288; }
    else if (i < 86016)  { p = s2;  off = i - 36864; }
    else if (i < 141312) { p = cw1; off = i - 86016; }
    else if (i < 196608) { p = rw1; off = i - 141312; }
    else if (i < 251904) { p = cw2; off = i - 196608; }
    else if (i < 307200) { p = rw2; off = i - 251904; }
    else                 { p = chw; off = i - 307200; }
    v = p[off];
  } else if (i < OFF_ROBJ) {
    int rel = i - OFF_WDT;
    int br = rel / 5184; int r2 = rel - br*5184;
    int lvl = r2 / 1728; int r3 = r2 - lvl*1728;
    int j = r3 / 192;    int c = r3 - j*192;
    const float* wd = br ? rwd : cwd;
    v = wd[lvl*1728 + c*9 + j];
  } else if (i < OFF_DWB) {
    int rel = i - OFF_ROBJ;
    int lvl = rel / 1536; int r2 = rel - lvl*1536;
    int co = r2 / 96;     int k = r2 - co*96;
    v = (co < 4) ? rpw[lvl*384 + co*96 + k] : (co == 4 ? opw[lvl*96 + k] : 0.f);
  } else {
    int rel = i - OFF_DWB;
    int br = rel / 576;  int r2 = rel - br*576;
    int lvl = r2 / 192;  int c = r2 - lvl*192;
    v = (br ? rbd : cbd)[lvl*192 + c];
  }
  dst[i] = (_Float16)v;
}

// ---------------------------------------------------------------------------
// Stem GEMM from NCHW fp32, fp16 MFMA. Output CHANNEL-GROUP-MAJOR [g][n][8].
// ---------------------------------------------------------------------------
__global__ __launch_bounds__(256) void stem_k(
    const float* __restrict__ x0, const float* __restrict__ x1,
    const float* __restrict__ x2, const _Float16* __restrict__ Wb,
    const float* __restrict__ sb0, const float* __restrict__ sb1,
    const float* __restrict__ sb2, _Float16* __restrict__ Out)
{
  const int m0 = blockIdx.x << 7;
  const int lvl = (m0 < 102400) ? 0 : (m0 < 128000 ? 1 : 2);
  const int CIN = (lvl==0)?128:(lvl==1?256:512);
  const int HW  = (lvl==0)?6400:(lvl==1?1600:400);
  const int noff= (lvl==0)?0:(lvl==1?102400:128000);
  const float* X = (lvl==0)?x0:(lvl==1?x1:x2);
  const _Float16* Wl = Wb + ((lvl==0)?0:(lvl==1?12288:36864));
  const float* bias = (lvl==0)?sb0:(lvl==1?sb1:sb2);

  int t=threadIdx.x, lane=t&63, wv=t>>6, mr=lane&15, quad=lane>>4;

  int idx[2];
  #pragma unroll
  for (int nt=0; nt<2; ++nt) {
    int n = m0 + wv*32 + nt*16 + mr;
    int m = n - noff; int b_ = m / HW; int p = m - b_*HW;
    idx[nt] = (b_*CIN + quad*8)*HW + p;
  }
  const _Float16* Ap = Wl + mr*CIN + quad*8;

  floatx4 zero = {0.f,0.f,0.f,0.f};
  floatx4 acc[6][2];
  #pragma unroll
  for (int i=0;i<6;++i)
    #pragma unroll
    for (int j=0;j<2;++j) acc[i][j] = zero;

  for (int k=0; k<CIN; k+=32) {
    half8 a[6], b[2];
    #pragma unroll
    for (int mt=0; mt<6; ++mt) a[mt] = *(const half8*)(Ap + mt*16*CIN);
    #pragma unroll
    for (int nt=0; nt<2; ++nt) {
      float f[8];
      #pragma unroll
      for (int j=0;j<8;++j) f[j] = X[idx[nt] + j*HW];
      half2v* bh = (half2v*)&b[nt];
      #pragma unroll
      for (int j=0;j<4;++j) bh[j] = pkrtz(f[2*j], f[2*j+1]);
    }
    #pragma unroll
    for (int mt=0; mt<6; ++mt)
      #pragma unroll
      for (int nt=0; nt<2; ++nt)
        acc[mt][nt] = __builtin_amdgcn_mfma_f32_16x16x32_f16(a[mt], b[nt], acc[mt][nt], 0, 0, 0);
    Ap += 32;
    #pragma unroll
    for (int nt=0; nt<2; ++nt) idx[nt] += 32*HW;
  }

  #pragma unroll
  for (int mt=0; mt<6; ++mt) {
    float4 bv = *(const float4*)(bias + mt*16 + quad*4);
    int co = mt*16 + quad*4;
    int g = co >> 3; int h = co & 7;
    #pragma unroll
    for (int nt=0; nt<2; ++nt) {
      int pos = m0 + wv*32 + nt*16 + mr;
      half4v o;
      o[0] = (_Float16)silu_f(acc[mt][nt][0] + bv.x);
      o[1] = (_Float16)silu_f(acc[mt][nt][1] + bv.y);
      o[2] = (_Float16)silu_f(acc[mt][nt][2] + bv.z);
      o[3] = (_Float16)silu_f(acc[mt][nt][3] + bv.w);
      *(half4v*)(Out + ((long)g*NDW + pos)*8 + h) = o;
    }
  }
}

// ---------------------------------------------------------------------------
// MEGAFUSED v2: expand GEMM + dw3x3 + proj GEMM + residual + heads.
// Change vs r14: NO stem LDS staging -- expand B-fragments read straight
// from global stemO (exact addresses staging used to copy). LDS = halo only
// [24][808] = 38.8KB -> 4 blocks/CU (2x resident waves). ldsP aliases halo
// behind the post-k-loop barrier. Halo group stride 808 decorrelates quads'
// bank phase.
// grid (2144, 2): [0,1600) lvl0, [1600,2000) lvl1, [2000,2144) lvl2
// (overlapping 8x8 tiles on 20x20, y0,x0 in {0,6,12}; dup writes identical).
// ---------------------------------------------------------------------------
#define PSTRIDE 104
#define HS2 808
__global__ __launch_bounds__(256, 4) void xfuse_k(
    const _Float16* __restrict__ stemO, const _Float16* __restrict__ wbf,
    const float* __restrict__ b1c, const float* __restrict__ b1r,
    const float* __restrict__ b2_c, const float* __restrict__ b2_r,
    const float* __restrict__ hb, const float* __restrict__ rb,
    const float* __restrict__ ob, float* __restrict__ out)
{
  __shared__ _Float16 halo[24*HS2];      // [g][100 entries][8ch] (+pad)
  _Float16* ldsP = halo;                 // alias after phase-3 barrier
  const int bz = blockIdx.y;
  const float* b2 = bz ? b2_r : b2_c;

  int orig = blockIdx.x;
  int bx = (orig & 7)*268 + (orig >> 3);   // bijective: 2144 = 8*268

  int lvl, W, HW, noff, a0;
  int b_, y0, x0;
  if (bx < 1600) {
    lvl = 0; W = 80; HW = 6400; noff = 0;      a0 = 0;
    b_ = bx / 100; int tl = bx - b_*100;
    y0 = (tl / 10) * 8; x0 = (tl - (tl/10)*10) * 8;
  } else if (bx < 2000) {
    lvl = 1; W = 40; HW = 1600; noff = 102400; a0 = 6400;
    int rel = bx - 1600; b_ = rel / 25; int tl = rel - b_*25;
    y0 = (tl / 5) * 8; x0 = (tl - (tl/5)*5) * 8;
  } else {
    lvl = 2; W = 20; HW = 400; noff = 128000; a0 = 8000;
    int rel = bx - 2000; b_ = rel / 9; int tl = rel - b_*9;
    int iy = tl / 3; int ix = tl - iy*3;
    y0 = iy*6; x0 = ix*6;                 // overlapping 8x8 tiles on 20x20
  }

  int t = threadIdx.x, lane = t & 63, wv = t >> 6;
  int mr = lane & 15, quad = lane >> 4;
  const int p = wv*16 + mr;              // this thread's tile-local position

  const _Float16* wT = wbf + OFF_WDT + bz*5184 + lvl*1728;
  const _Float16* bB = wbf + OFF_DWB + bz*576 + lvl*192;
  const _Float16* Ap = wbf + OFF_W2 + bz*55296 + lvl*18432 + ((long)mr)*192 + quad*8;

  // this thread's global position n (center tile)
  const int n = noff + b_*HW + (y0 + (p>>3))*W + x0 + (p&7);

  // resid prefetch (consumed after phase 3)
  half4v rsv[6];
  #pragma unroll
  for (int mt=0; mt<6; ++mt) {
    int co = mt*16 + quad*4;
    int g = co >> 3; int h = co & 7;
    rsv[mt] = *(const half4v*)(stemO + ((long)g*NDW + n)*8 + h);
  }

  // ---- 1. expand GEMM: W1 (reg-hoisted) x stem (DIRECT GLOBAL) -> halo ----
  {
    const _Float16* W1 = wbf + OFF_W1 + bz*55296 + lvl*18432;
    const float* bp1 = (bz ? b1r : b1c) + lvl*192;
    // hoist A-frags: 3 M-tiles x 3 k-steps
    half8 wf[3][3];
    #pragma unroll
    for (int m3 = 0; m3 < 3; ++m3)
      #pragma unroll
      for (int ks = 0; ks < 3; ++ks)
        wf[m3][ks] = *(const half8*)(W1 + (long)((wv*3+m3)*16 + mr)*96 + ks*32 + quad*8);

    #pragma unroll
    for (int nt = 0; nt < 7; ++nt) {
      int ee = nt*16 + mr;
      int e = ee < 100 ? ee : 99;
      int hy = e / 10, hx = e - hy*10;
      int ay = y0 - 1 + hy, ax = x0 - 1 + hx;
      bool oob = ((unsigned)ay >= (unsigned)W) || ((unsigned)ax >= (unsigned)W);
      int yy = ay < 0 ? 0 : (ay >= W ? W-1 : ay);
      int xx = ax < 0 ? 0 : (ax >= W ? W-1 : ax);
      long ne = (long)noff + (long)b_*HW + yy*W + xx;

      floatx4 acc[3];
      #pragma unroll
      for (int m3 = 0; m3 < 3; ++m3) acc[m3] = floatx4{0.f,0.f,0.f,0.f};
      #pragma unroll
      for (int ks = 0; ks < 3; ++ks) {
        half8 af = *(const half8*)(stemO + ((long)(ks*4+quad)*NDW + ne)*8);
        #pragma unroll
        for (int m3 = 0; m3 < 3; ++m3)
          acc[m3] = __builtin_amdgcn_mfma_f32_16x16x32_f16(wf[m3][ks], af, acc[m3], 0, 0, 0);
      }
      if (ee < 100) {
        #pragma unroll
        for (int m3 = 0; m3 < 3; ++m3) {
          int co = (wv*3+m3)*16 + quad*4;
          float4 bv = *(const float4*)(bp1 + co);
          half4v o;
          if (oob) {
            o[0]=o[1]=o[2]=o[3]=(_Float16)0.f;
          } else {
            o[0] = (_Float16)silu_f(acc[m3][0] + bv.x);
            o[1] = (_Float16)silu_f(acc[m3][1] + bv.y);
            o[2] = (_Float16)silu_f(acc[m3][2] + bv.z);
            o[3] = (_Float16)silu_f(acc[m3][3] + bv.w);
          }
          *(half4v*)(halo + (co>>3)*HS2 + ee*8 + (co&7)) = o;
        }
      }
    }
  }
  __syncthreads();   // halo complete

  // ---- 2. fused dw + proj k-loop, taps from halo LDS ----
  floatx4 pacc[6];
  #pragma unroll
  for (int j=0;j<6;++j) pacc[j] = floatx4{0.f,0.f,0.f,0.f};
  {
    const int ty = p >> 3, tx = p & 7;
    const _Float16* hb0 = halo + (ty*10 + tx)*8;   // entry (ty,tx) base
    for (int k = 0; k < 6; ++k) {
      const int g = 4*k + quad;
      const _Float16* hg = hb0 + g*HS2;
      const _Float16* wp = wT + g*8;

      half8 a[9], w[9];
      #pragma unroll
      for (int dy = 0; dy < 3; ++dy)
        #pragma unroll
        for (int dx = 0; dx < 3; ++dx)
          a[dy*3+dx] = *(const half8*)(hg + (dy*10 + dx)*8);
      #pragma unroll
      for (int tap = 0; tap < 9; ++tap)
        w[tap] = *(const half8*)(wp + tap*192);
      half8 bv8 = *(const half8*)(bB + g*8);
      half8 wfp[6];
      #pragma unroll
      for (int mt = 0; mt < 6; ++mt)
        wfp[mt] = *(const half8*)(Ap + (long)mt*16*192 + k*32);

      half2v ac0 = {bv8[0], bv8[1]};
      half2v ac1 = {bv8[2], bv8[3]};
      half2v ac2 = {bv8[4], bv8[5]};
      half2v ac3 = {bv8[6], bv8[7]};
      #pragma unroll
      for (int tap = 0; tap < 9; ++tap) {
        ac0 += half2v{a[tap][0],a[tap][1]} * half2v{w[tap][0],w[tap][1]};
        ac1 += half2v{a[tap][2],a[tap][3]} * half2v{w[tap][2],w[tap][3]};
        ac2 += half2v{a[tap][4],a[tap][5]} * half2v{w[tap][4],w[tap][5]};
        ac3 += half2v{a[tap][6],a[tap][7]} * half2v{w[tap][6],w[tap][7]};
      }
      half8 af;
      {
        half2v* oh = (half2v*)&af;
        oh[0] = pkrtz(silu_f((float)ac0[0]), silu_f((float)ac0[1]));
        oh[1] = pkrtz(silu_f((float)ac1[0]), silu_f((float)ac1[1]));
        oh[2] = pkrtz(silu_f((float)ac2[0]), silu_f((float)ac2[1]));
        oh[3] = pkrtz(silu_f((float)ac3[0]), silu_f((float)ac3[1]));
      }
      #pragma unroll
      for (int mt = 0; mt < 6; ++mt)
        pacc[mt] = __builtin_amdgcn_mfma_f32_16x16x32_f16(wfp[mt], af, pacc[mt], 0, 0, 0);
    }
  }
  __syncthreads();   // halo reads done -> ldsP may overwrite

  // ---- 3. epilogue: + bias + prefetched residual -> ldsP [pos][co] ----
  {
    const float* bp2 = b2 + lvl*96;
    #pragma unroll
    for (int mt=0; mt<6; ++mt) {
      int co = mt*16 + quad*4;
      float4 bv = *(const float4*)(bp2 + co);
      half4v o;
      o[0] = (_Float16)(pacc[mt][0] + bv.x + (float)rsv[mt][0]);
      o[1] = (_Float16)(pacc[mt][1] + bv.y + (float)rsv[mt][1]);
      o[2] = (_Float16)(pacc[mt][2] + bv.z + (float)rsv[mt][2]);
      o[3] = (_Float16)(pacc[mt][3] + bv.w + (float)rsv[mt][3]);
      *(half4v*)(ldsP + p*PSTRIDE + co) = o;
    }
  }
  // heads read only this wave's 16 rows -> no barrier (same-wave ds ordering).

  // ---- heads ----
  if (bz == 0) {
    const _Float16* Bp = wbf + OFF_HEAD + lvl*7680 + ((long)mr)*96 + quad*8;
    const float* bp = hb + lvl*80;
    floatx4 acc[5];
    #pragma unroll
    for (int j=0;j<5;++j) acc[j] = floatx4{0.f,0.f,0.f,0.f};

    #pragma unroll
    for (int k=0; k<3; ++k) {
      half8 a = *(const half8*)(ldsP + (wv*16 + mr)*PSTRIDE + k*32 + quad*8);
      half8 b[5];
      #pragma unroll
      for (int nt=0; nt<5; ++nt)
        b[nt] = *(const half8*)(Bp + (long)nt*16*96 + k*32);
      #pragma unroll
      for (int nt=0; nt<5; ++nt)
        acc[nt] = __builtin_amdgcn_mfma_f32_16x16x32_f16(a, b[nt], acc[nt], 0, 0, 0);
    }

    #pragma unroll
    for (int nt=0; nt<5; ++nt) {
      int co = nt*16 + mr;
      float bv = bp[co];
      #pragma unroll
      for (int r=0; r<4; ++r) {
        int pq = wv*16 + quad*4 + r;       // tile-local position
        int rpp = (y0 + (pq>>3))*W + x0 + (pq&7);
        out[((long)(b_*8400 + a0 + rpp))*85 + 5 + co] = sigm_f(acc[nt][r] + bv);
      }
    }
  } else {
    const _Float16* Bp = wbf + OFF_ROBJ + lvl*1536 + ((long)mr)*96 + quad*8;
    float bv = (mr < 4) ? rb[lvl*4 + mr] : ((mr == 4) ? ob[lvl] : 0.f);
    float sc = (lvl==0) ? 8.f : (lvl==1 ? 16.f : 32.f);
    floatx4 acc = {0.f,0.f,0.f,0.f};
    #pragma unroll
    for (int k=0; k<3; ++k) {
      half8 a = *(const half8*)(ldsP + (wv*16 + mr)*PSTRIDE + k*32 + quad*8);
      half8 b = *(const half8*)(Bp + k*32);
      acc = __builtin_amdgcn_mfma_f32_16x16x32_f16(a, b, acc, 0, 0, 0);
    }
    #pragma unroll
    for (int r=0; r<4; ++r) {
      int pq = wv*16 + quad*4 + r;
      int yy = y0 + (pq>>3); int xx = x0 + (pq&7);
      int rpp = yy*W + xx;
      float v = acc[r] + bv;
      float o;
      if      (mr == 0) o = (v + (float)xx)*sc;
      else if (mr == 1) o = (v + (float)yy)*sc;
      else if (mr <  4) o = __expf(v)*sc;
      else              o = sigm_f(v);
      if (mr < 5)
        out[((long)(b_*8400 + a0 + rpp))*85 + mr] = o;
    }
  }
}

extern "C" void kernel_launch(void* const* d_in, const int* in_sizes, int n_in,
                              void* d_out, int out_size, void* d_ws, size_t ws_size,
                              hipStream_t stream)
{
  bool dict = (in_sizes[1] == 96*128);
  const float* X[3]; const float* SW[3]; const float* SB[3];
  if (dict) {
    X[0]=(const float*)d_in[0]; SW[0]=(const float*)d_in[1]; SB[0]=(const float*)d_in[2];
    X[1]=(const float*)d_in[3]; SW[1]=(const float*)d_in[4]; SB[1]=(const float*)d_in[5];
    X[2]=(const float*)d_in[6]; SW[2]=(const float*)d_in[7]; SB[2]=(const float*)d_in[8];
  } else {
    X[0]=(const float*)d_in[0]; X[1]=(const float*)d_in[1]; X[2]=(const float*)d_in[2];
    SW[0]=(const float*)d_in[3]; SB[0]=(const float*)d_in[4];
    SW[1]=(const float*)d_in[5]; SB[1]=(const float*)d_in[6];
    SW[2]=(const float*)d_in[7]; SB[2]=(const float*)d_in[8];
  }
  const float* br_w1[2] = {(const float*)d_in[9],  (const float*)d_in[15]};
  const float* br_b1[2] = {(const float*)d_in[10], (const float*)d_in[16]};
  const float* br_wd[2] = {(const float*)d_in[11], (const float*)d_in[17]};
  const float* br_bd[2] = {(const float*)d_in[12], (const float*)d_in[18]};
  const float* br_w2[2] = {(const float*)d_in[13], (const float*)d_in[19]};
  const float* br_b2[2] = {(const float*)d_in[14], (const float*)d_in[20]};
  const float* clsp_w=(const float*)d_in[21]; const float* clsp_b=(const float*)d_in[22];
  const float* regp_w=(const float*)d_in[23]; const float* regp_b=(const float*)d_in[24];
  const float* objp_w=(const float*)d_in[25]; const float* objp_b=(const float*)d_in[26];

  float* out = (float*)d_out;

  // workspace (fp16 units): wbf 346,368 + stemO 12,902,400 = 26.5 MB
  _Float16* wbf   = (_Float16*)d_ws;
  _Float16* stemO = wbf + WTOT;

  // 1. weights/bias -> fp16 blob
  wconv_k<<<1353,256,0,stream>>>(SW[0],SW[1],SW[2],br_w1[0],br_w1[1],
                                 br_w2[0],br_w2[1],clsp_w,br_wd[0],br_wd[1],
                                 regp_w,objp_w,br_bd[0],br_bd[1],wbf);

  // 2. stem GEMM straight from NCHW fp32, channel-major output
  stem_k<<<1050,256,0,stream>>>(X[0],X[1],X[2],wbf,SB[0],SB[1],SB[2],stemO);

  // 3. MEGAFUSED expand + dw3x3 + project + residual + heads
  xfuse_k<<<dim3(2144,2),256,0,stream>>>(
      stemO, wbf, br_b1[0], br_b1[1], br_b2[0], br_b2[1],
      clsp_b, regp_b, objp_b, out);
}

// Round 16
// 208.388 us; speedup vs baseline: 1.2303x; 1.0126x over previous
//
#include <hip/hip_runtime.h>
#include <hip/hip_fp16.h>

typedef unsigned int uint32;
using half2v  = __attribute__((ext_vector_type(2))) _Float16;
using half4v  = __attribute__((ext_vector_type(4))) _Float16;
using half8   = __attribute__((ext_vector_type(8))) _Float16;
using floatx4 = __attribute__((ext_vector_type(4))) float;

__device__ __forceinline__ float sigm_f(float x){
  return __builtin_amdgcn_rcpf(1.0f + __expf(-x));
}
__device__ __forceinline__ float silu_f(float x){ return x * sigm_f(x); }

__device__ __forceinline__ half2v pkrtz(float a, float b){
  return __builtin_bit_cast(half2v, __builtin_amdgcn_cvt_pkrtz(a, b));
}

// packed fp16 silu: 2 elements, ~7 VALU (vs ~13 for cvt+f32 path).
// Overflow is graceful: exp(|x| big) -> inf -> rcp -> 0 -> silu tail = 0.
__device__ __forceinline__ half2v silu_h2(half2v v){
  __half2 hv = __builtin_bit_cast(__half2, v);
  __half2 e  = h2exp(__hneg2(hv));
  __half2 r  = h2rcp(__hadd2(e, __float2half2_rn(1.0f)));
  return __builtin_bit_cast(half2v, __hmul2(hv, r));
}

// ---------------------------------------------------------------------------
// fp16 weight blob layout (element offsets):
//   0      stemW0..2 | 86016 w1 (cls/reg) | 196608 w2 | 307200 clsp_w
//   330240 wdT | 340608 regobj | 345216 dwbias | 346368 total
// ---------------------------------------------------------------------------
#define OFF_W1    86016
#define OFF_W2    196608
#define OFF_HEAD  307200
#define OFF_WDT   330240
#define OFF_ROBJ  340608
#define OFF_DWB   345216
#define WTOT      346368

// stem output, CHANNEL-GROUP-MAJOR: [g=12][n=134400][8ch]
#define NDW  134400

__global__ __launch_bounds__(256) void wconv_k(
    const float* __restrict__ s0, const float* __restrict__ s1,
    const float* __restrict__ s2, const float* __restrict__ cw1,
    const float* __restrict__ rw1, const float* __restrict__ cw2,
    const float* __restrict__ rw2, const float* __restrict__ chw,
    const float* __restrict__ cwd, const float* __restrict__ rwd,
    const float* __restrict__ rpw, const float* __restrict__ opw,
    const float* __restrict__ cbd, const float* __restrict__ rbd,
    _Float16* __restrict__ dst)
{
  int i = blockIdx.x*256 + threadIdx.x;
  if (i >= WTOT) return;
  float v;
  if (i < OFF_WDT) {
    const float* p; int off;
    if      (i < 12288)  { p = s0;  off = i; }
    else if (i < 36864)  { p = s1;  off = i - 12288; }
    else if (i < 86016)  { p = s2;  off = i - 36864; }
    else if (i < 141312) { p = cw1; off = i - 86016; }
    else if (i < 196608) { p = rw1; off = i - 141312; }
    else if (i < 251904) { p = cw2; off = i - 196608; }
    else if (i < 307200) { p = rw2; off = i - 251904; }
    else                 { p = chw; off = i - 307200; }
    v = p[off];
  } else if (i < OFF_ROBJ) {
    int rel = i - OFF_WDT;
    int br = rel / 5184; int r2 = rel - br*5184;
    int lvl = r2 / 1728; int r3 = r2 - lvl*1728;
    int j = r3 / 192;    int c = r3 - j*192;
    const float* wd = br ? rwd : cwd;
    v = wd[lvl*1728 + c*9 + j];
  } else if (i < OFF_DWB) {
    int rel = i - OFF_ROBJ;
    int lvl = rel / 1536; int r2 = rel - lvl*1536;
    int co = r2 / 96;     int k = r2 - co*96;
    v = (co < 4) ? rpw[lvl*384 + co*96 + k] : (co == 4 ? opw[lvl*96 + k] : 0.f);
  } else {
    int rel = i - OFF_DWB;
    int br = rel / 576;  int r2 = rel - br*576;
    int lvl = r2 / 192;  int c = r2 - lvl*192;
    v = (br ? rbd : cbd)[lvl*192 + c];
  }
  dst[i] = (_Float16)v;
}

// ---------------------------------------------------------------------------
// Stem GEMM from NCHW fp32, fp16 MFMA. Output CHANNEL-GROUP-MAJOR [g][n][8].
// ---------------------------------------------------------------------------
__global__ __launch_bounds__(256) void stem_k(
    const float* __restrict__ x0, const float* __restrict__ x1,
    const float* __restrict__ x2, const _Float16* __restrict__ Wb,
    const float* __restrict__ sb0, const float* __restrict__ sb1,
    const float* __restrict__ sb2, _Float16* __restrict__ Out)
{
  const int m0 = blockIdx.x << 7;
  const int lvl = (m0 < 102400) ? 0 : (m0 < 128000 ? 1 : 2);
  const int CIN = (lvl==0)?128:(lvl==1?256:512);
  const int HW  = (lvl==0)?6400:(lvl==1?1600:400);
  const int noff= (lvl==0)?0:(lvl==1?102400:128000);
  const float* X = (lvl==0)?x0:(lvl==1?x1:x2);
  const _Float16* Wl = Wb + ((lvl==0)?0:(lvl==1?12288:36864));
  const float* bias = (lvl==0)?sb0:(lvl==1?sb1:sb2);

  int t=threadIdx.x, lane=t&63, wv=t>>6, mr=lane&15, quad=lane>>4;

  int idx[2];
  #pragma unroll
  for (int nt=0; nt<2; ++nt) {
    int n = m0 + wv*32 + nt*16 + mr;
    int m = n - noff; int b_ = m / HW; int p = m - b_*HW;
    idx[nt] = (b_*CIN + quad*8)*HW + p;
  }
  const _Float16* Ap = Wl + mr*CIN + quad*8;

  floatx4 zero = {0.f,0.f,0.f,0.f};
  floatx4 acc[6][2];
  #pragma unroll
  for (int i=0;i<6;++i)
    #pragma unroll
    for (int j=0;j<2;++j) acc[i][j] = zero;

  for (int k=0; k<CIN; k+=32) {
    half8 a[6], b[2];
    #pragma unroll
    for (int mt=0; mt<6; ++mt) a[mt] = *(const half8*)(Ap + mt*16*CIN);
    #pragma unroll
    for (int nt=0; nt<2; ++nt) {
      float f[8];
      #pragma unroll
      for (int j=0;j<8;++j) f[j] = X[idx[nt] + j*HW];
      half2v* bh = (half2v*)&b[nt];
      #pragma unroll
      for (int j=0;j<4;++j) bh[j] = pkrtz(f[2*j], f[2*j+1]);
    }
    #pragma unroll
    for (int mt=0; mt<6; ++mt)
      #pragma unroll
      for (int nt=0; nt<2; ++nt)
        acc[mt][nt] = __builtin_amdgcn_mfma_f32_16x16x32_f16(a[mt], b[nt], acc[mt][nt], 0, 0, 0);
    Ap += 32;
    #pragma unroll
    for (int nt=0; nt<2; ++nt) idx[nt] += 32*HW;
  }

  #pragma unroll
  for (int mt=0; mt<6; ++mt) {
    float4 bv = *(const float4*)(bias + mt*16 + quad*4);
    int co = mt*16 + quad*4;
    int g = co >> 3; int h = co & 7;
    #pragma unroll
    for (int nt=0; nt<2; ++nt) {
      int pos = m0 + wv*32 + nt*16 + mr;
      half4v o;
      o[0] = (_Float16)silu_f(acc[mt][nt][0] + bv.x);
      o[1] = (_Float16)silu_f(acc[mt][nt][1] + bv.y);
      o[2] = (_Float16)silu_f(acc[mt][nt][2] + bv.z);
      o[3] = (_Float16)silu_f(acc[mt][nt][3] + bv.w);
      *(half4v*)(Out + g*NDW*8 + pos*8 + h) = o;
    }
  }
}

// ---------------------------------------------------------------------------
// MEGAFUSED v3 (r15 structure) with issue-count reduction:
//  - packed fp16 silu (h2exp/h2rcp) in expand epilogue + dw repack
//  - int32 addressing everywhere (no 64-bit per-lane address chains)
// LDS = halo [24][808] = 38.8KB -> 4 blocks/CU; ldsP aliases halo.
// grid (2144, 2): [0,1600) lvl0, [1600,2000) lvl1, [2000,2144) lvl2
// (overlapping 8x8 tiles on 20x20, y0,x0 in {0,6,12}; dup writes identical).
// ---------------------------------------------------------------------------
#define PSTRIDE 104
#define HS2 808
__global__ __launch_bounds__(256, 4) void xfuse_k(
    const _Float16* __restrict__ stemO, const _Float16* __restrict__ wbf,
    const float* __restrict__ b1c, const float* __restrict__ b1r,
    const float* __restrict__ b2_c, const float* __restrict__ b2_r,
    const float* __restrict__ hb, const float* __restrict__ rb,
    const float* __restrict__ ob, float* __restrict__ out)
{
  __shared__ _Float16 halo[24*HS2];      // [g][100 entries][8ch] (+pad)
  _Float16* ldsP = halo;                 // alias after phase-2 barrier
  const int bz = blockIdx.y;
  const float* b2 = bz ? b2_r : b2_c;

  int orig = blockIdx.x;
  int bx = (orig & 7)*268 + (orig >> 3);   // bijective: 2144 = 8*268

  int lvl, W, HW, noff, a0;
  int b_, y0, x0;
  if (bx < 1600) {
    lvl = 0; W = 80; HW = 6400; noff = 0;      a0 = 0;
    b_ = bx / 100; int tl = bx - b_*100;
    y0 = (tl / 10) * 8; x0 = (tl - (tl/10)*10) * 8;
  } else if (bx < 2000) {
    lvl = 1; W = 40; HW = 1600; noff = 102400; a0 = 6400;
    int rel = bx - 1600; b_ = rel / 25; int tl = rel - b_*25;
    y0 = (tl / 5) * 8; x0 = (tl - (tl/5)*5) * 8;
  } else {
    lvl = 2; W = 20; HW = 400; noff = 128000; a0 = 8000;
    int rel = bx - 2000; b_ = rel / 9; int tl = rel - b_*9;
    int iy = tl / 3; int ix = tl - iy*3;
    y0 = iy*6; x0 = ix*6;                 // overlapping 8x8 tiles on 20x20
  }

  int t = threadIdx.x, lane = t & 63, wv = t >> 6;
  int mr = lane & 15, quad = lane >> 4;
  const int p = wv*16 + mr;              // this thread's tile-local position

  const _Float16* wT = wbf + OFF_WDT + bz*5184 + lvl*1728;
  const _Float16* bB = wbf + OFF_DWB + bz*576 + lvl*192;
  const _Float16* Ap = wbf + OFF_W2 + bz*55296 + lvl*18432 + mr*192 + quad*8;

  // this thread's global position n (center tile)
  const int n = noff + b_*HW + (y0 + (p>>3))*W + x0 + (p&7);

  // resid prefetch (consumed after phase 2)
  half4v rsv[6];
  #pragma unroll
  for (int mt=0; mt<6; ++mt) {
    int co = mt*16 + quad*4;
    int g = co >> 3; int h = co & 7;
    rsv[mt] = *(const half4v*)(stemO + g*(NDW*8) + n*8 + h);
  }

  // ---- 1. expand GEMM: W1 (reg-hoisted) x stem (direct global) -> halo ----
  {
    const _Float16* W1 = wbf + OFF_W1 + bz*55296 + lvl*18432;
    const float* bp1 = (bz ? b1r : b1c) + lvl*192;
    // hoist A-frags: 3 M-tiles x 3 k-steps
    half8 wf[3][3];
    #pragma unroll
    for (int m3 = 0; m3 < 3; ++m3)
      #pragma unroll
      for (int ks = 0; ks < 3; ++ks)
        wf[m3][ks] = *(const half8*)(W1 + ((wv*3+m3)*16 + mr)*96 + ks*32 + quad*8);

    #pragma unroll
    for (int nt = 0; nt < 7; ++nt) {
      int ee = nt*16 + mr;
      int e = ee < 100 ? ee : 99;
      int hy = e / 10, hx = e - hy*10;
      int ay = y0 - 1 + hy, ax = x0 - 1 + hx;
      bool oob = ((unsigned)ay >= (unsigned)W) || ((unsigned)ax >= (unsigned)W);
      int yy = ay < 0 ? 0 : (ay >= W ? W-1 : ay);
      int xx = ax < 0 ? 0 : (ax >= W ? W-1 : ax);
      int ne = noff + b_*HW + yy*W + xx;

      floatx4 acc[3];
      #pragma unroll
      for (int m3 = 0; m3 < 3; ++m3) acc[m3] = floatx4{0.f,0.f,0.f,0.f};
      #pragma unroll
      for (int ks = 0; ks < 3; ++ks) {
        half8 af = *(const half8*)(stemO + (ks*4+quad)*(NDW*8) + ne*8);
        #pragma unroll
        for (int m3 = 0; m3 < 3; ++m3)
          acc[m3] = __builtin_amdgcn_mfma_f32_16x16x32_f16(wf[m3][ks], af, acc[m3], 0, 0, 0);
      }
      if (ee < 100) {
        #pragma unroll
        for (int m3 = 0; m3 < 3; ++m3) {
          int co = (wv*3+m3)*16 + quad*4;
          float4 bv = *(const float4*)(bp1 + co);
          half4v o;
          if (oob) {
            o[0]=o[1]=o[2]=o[3]=(_Float16)0.f;
          } else {
            half2v p01 = silu_h2(pkrtz(acc[m3][0] + bv.x, acc[m3][1] + bv.y));
            half2v p23 = silu_h2(pkrtz(acc[m3][2] + bv.z, acc[m3][3] + bv.w));
            o[0]=p01[0]; o[1]=p01[1]; o[2]=p23[0]; o[3]=p23[1];
          }
          *(half4v*)(halo + (co>>3)*HS2 + ee*8 + (co&7)) = o;
        }
      }
    }
  }
  __syncthreads();   // halo complete

  // ---- 2. fused dw + proj k-loop, taps from halo LDS (all-fp16 math) ----
  floatx4 pacc[6];
  #pragma unroll
  for (int j=0;j<6;++j) pacc[j] = floatx4{0.f,0.f,0.f,0.f};
  {
    const int ty = p >> 3, tx = p & 7;
    const _Float16* hb0 = halo + (ty*10 + tx)*8;   // entry (ty,tx) base
    for (int k = 0; k < 6; ++k) {
      const int g = 4*k + quad;
      const _Float16* hg = hb0 + g*HS2;
      const _Float16* wp = wT + g*8;

      half8 a[9], w[9];
      #pragma unroll
      for (int dy = 0; dy < 3; ++dy)
        #pragma unroll
        for (int dx = 0; dx < 3; ++dx)
          a[dy*3+dx] = *(const half8*)(hg + (dy*10 + dx)*8);
      #pragma unroll
      for (int tap = 0; tap < 9; ++tap)
        w[tap] = *(const half8*)(wp + tap*192);
      half8 bv8 = *(const half8*)(bB + g*8);
      half8 wfp[6];
      #pragma unroll
      for (int mt = 0; mt < 6; ++mt)
        wfp[mt] = *(const half8*)(Ap + mt*16*192 + k*32);

      half2v ac0 = {bv8[0], bv8[1]};
      half2v ac1 = {bv8[2], bv8[3]};
      half2v ac2 = {bv8[4], bv8[5]};
      half2v ac3 = {bv8[6], bv8[7]};
      #pragma unroll
      for (int tap = 0; tap < 9; ++tap) {
        ac0 += half2v{a[tap][0],a[tap][1]} * half2v{w[tap][0],w[tap][1]};
        ac1 += half2v{a[tap][2],a[tap][3]} * half2v{w[tap][2],w[tap][3]};
        ac2 += half2v{a[tap][4],a[tap][5]} * half2v{w[tap][4],w[tap][5]};
        ac3 += half2v{a[tap][6],a[tap][7]} * half2v{w[tap][6],w[tap][7]};
      }
      half8 af;
      {
        half2v* oh = (half2v*)&af;
        oh[0] = silu_h2(ac0);
        oh[1] = silu_h2(ac1);
        oh[2] = silu_h2(ac2);
        oh[3] = silu_h2(ac3);
      }
      #pragma unroll
      for (int mt = 0; mt < 6; ++mt)
        pacc[mt] = __builtin_amdgcn_mfma_f32_16x16x32_f16(wfp[mt], af, pacc[mt], 0, 0, 0);
    }
  }
  __syncthreads();   // halo reads done -> ldsP may overwrite

  // ---- 3. epilogue: + bias + prefetched residual -> ldsP [pos][co] ----
  {
    const float* bp2 = b2 + lvl*96;
    #pragma unroll
    for (int mt=0; mt<6; ++mt) {
      int co = mt*16 + quad*4;
      float4 bv = *(const float4*)(bp2 + co);
      half4v o;
      o[0] = (_Float16)(pacc[mt][0] + bv.x + (float)rsv[mt][0]);
      o[1] = (_Float16)(pacc[mt][1] + bv.y + (float)rsv[mt][1]);
      o[2] = (_Float16)(pacc[mt][2] + bv.z + (float)rsv[mt][2]);
      o[3] = (_Float16)(pacc[mt][3] + bv.w + (float)rsv[mt][3]);
      *(half4v*)(ldsP + p*PSTRIDE + co) = o;
    }
  }
  // heads read only this wave's 16 rows -> no barrier (same-wave ds ordering).

  // ---- heads ----
  if (bz == 0) {
    const _Float16* Bp = wbf + OFF_HEAD + lvl*7680 + mr*96 + quad*8;
    const float* bp = hb + lvl*80;
    floatx4 acc[5];
    #pragma unroll
    for (int j=0;j<5;++j) acc[j] = floatx4{0.f,0.f,0.f,0.f};

    #pragma unroll
    for (int k=0; k<3; ++k) {
      half8 a = *(const half8*)(ldsP + (wv*16 + mr)*PSTRIDE + k*32 + quad*8);
      half8 b[5];
      #pragma unroll
      for (int nt=0; nt<5; ++nt)
        b[nt] = *(const half8*)(Bp + nt*16*96 + k*32);
      #pragma unroll
      for (int nt=0; nt<5; ++nt)
        acc[nt] = __builtin_amdgcn_mfma_f32_16x16x32_f16(a, b[nt], acc[nt], 0, 0, 0);
    }

    #pragma unroll
    for (int nt=0; nt<5; ++nt) {
      int co = nt*16 + mr;
      float bv = bp[co];
      #pragma unroll
      for (int r=0; r<4; ++r) {
        int pq = wv*16 + quad*4 + r;       // tile-local position
        int rpp = (y0 + (pq>>3))*W + x0 + (pq&7);
        out[(b_*8400 + a0 + rpp)*85 + 5 + co] = sigm_f(acc[nt][r] + bv);
      }
    }
  } else {
    const _Float16* Bp = wbf + OFF_ROBJ + lvl*1536 + mr*96 + quad*8;
    float bv = (mr < 4) ? rb[lvl*4 + mr] : ((mr == 4) ? ob[lvl] : 0.f);
    float sc = (lvl==0) ? 8.f : (lvl==1 ? 16.f : 32.f);
    floatx4 acc = {0.f,0.f,0.f,0.f};
    #pragma unroll
    for (int k=0; k<3; ++k) {
      half8 a = *(const half8*)(ldsP + (wv*16 + mr)*PSTRIDE + k*32 + quad*8);
      half8 b = *(const half8*)(Bp + k*32);
      acc = __builtin_amdgcn_mfma_f32_16x16x32_f16(a, b, acc, 0, 0, 0);
    }
    #pragma unroll
    for (int r=0; r<4; ++r) {
      int pq = wv*16 + quad*4 + r;
      int yy = y0 + (pq>>3); int xx = x0 + (pq&7);
      int rpp = yy*W + xx;
      float v = acc[r] + bv;
      float o;
      if      (mr == 0) o = (v + (float)xx)*sc;
      else if (mr == 1) o = (v + (float)yy)*sc;
      else if (mr <  4) o = __expf(v)*sc;
      else              o = sigm_f(v);
      if (mr < 5)
        out[(b_*8400 + a0 + rpp)*85 + mr] = o;
    }
  }
}

extern "C" void kernel_launch(void* const* d_in, const int* in_sizes, int n_in,
                              void* d_out, int out_size, void* d_ws, size_t ws_size,
                              hipStream_t stream)
{
  bool dict = (in_sizes[1] == 96*128);
  const float* X[3]; const float* SW[3]; const float* SB[3];
  if (dict) {
    X[0]=(const float*)d_in[0]; SW[0]=(const float*)d_in[1]; SB[0]=(const float*)d_in[2];
    X[1]=(const float*)d_in[3]; SW[1]=(const float*)d_in[4]; SB[1]=(const float*)d_in[5];
    X[2]=(const float*)d_in[6]; SW[2]=(const float*)d_in[7]; SB[2]=(const float*)d_in[8];
  } else {
    X[0]=(const float*)d_in[0]; X[1]=(const float*)d_in[1]; X[2]=(const float*)d_in[2];
    SW[0]=(const float*)d_in[3]; SB[0]=(const float*)d_in[4];
    SW[1]=(const float*)d_in[5]; SB[1]=(const float*)d_in[6];
    SW[2]=(const float*)d_in[7]; SB[2]=(const float*)d_in[8];
  }
  const float* br_w1[2] = {(const float*)d_in[9],  (const float*)d_in[15]};
  const float* br_b1[2] = {(const float*)d_in[10], (const float*)d_in[16]};
  const float* br_wd[2] = {(const float*)d_in[11], (const float*)d_in[17]};
  const float* br_bd[2] = {(const float*)d_in[12], (const float*)d_in[18]};
  const float* br_w2[2] = {(const float*)d_in[13], (const float*)d_in[19]};
  const float* br_b2[2] = {(const float*)d_in[14], (const float*)d_in[20]};
  const float* clsp_w=(const float*)d_in[21]; const float* clsp_b=(const float*)d_in[22];
  const float* regp_w=(const float*)d_in[23]; const float* regp_b=(const float*)d_in[24];
  const float* objp_w=(const float*)d_in[25]; const float* objp_b=(const float*)d_in[26];

  float* out = (float*)d_out;

  // workspace (fp16 units): wbf 346,368 + stemO 12,902,400 = 26.5 MB
  _Float16* wbf   = (_Float16*)d_ws;
  _Float16* stemO = wbf + WTOT;

  // 1. weights/bias -> fp16 blob
  wconv_k<<<1353,256,0,stream>>>(SW[0],SW[1],SW[2],br_w1[0],br_w1[1],
                                 br_w2[0],br_w2[1],clsp_w,br_wd[0],br_wd[1],
                                 regp_w,objp_w,br_bd[0],br_bd[1],wbf);

  // 2. stem GEMM straight from NCHW fp32, channel-major output
  stem_k<<<1050,256,0,stream>>>(X[0],X[1],X[2],wbf,SB[0],SB[1],SB[2],stemO);

  // 3. MEGAFUSED expand + dw3x3 + project + residual + heads
  xfuse_k<<<dim3(2144,2),256,0,stream>>>(
      stemO, wbf, br_b1[0], br_b1[1], br_b2[0], br_b2[1],
      clsp_b, regp_b, objp_b, out);
}

// Round 17
// 186.054 us; speedup vs baseline: 1.3780x; 1.1200x over previous
//
#include <hip/hip_runtime.h>
#include <hip/hip_fp16.h>

typedef unsigned int uint32;
using half2v  = __attribute__((ext_vector_type(2))) _Float16;
using half4v  = __attribute__((ext_vector_type(4))) _Float16;
using half8   = __attribute__((ext_vector_type(8))) _Float16;
using floatx4 = __attribute__((ext_vector_type(4))) float;

__device__ __forceinline__ float sigm_f(float x){
  return __builtin_amdgcn_rcpf(1.0f + __expf(-x));
}
__device__ __forceinline__ float silu_f(float x){ return x * sigm_f(x); }

__device__ __forceinline__ half2v pkrtz(float a, float b){
  return __builtin_bit_cast(half2v, __builtin_amdgcn_cvt_pkrtz(a, b));
}

// packed fp16 silu: 2 elements; overflow is graceful (exp->inf->rcp->0).
__device__ __forceinline__ half2v silu_h2(half2v v){
  __half2 hv = __builtin_bit_cast(__half2, v);
  __half2 e  = h2exp(__hneg2(hv));
  __half2 r  = h2rcp(__hadd2(e, __float2half2_rn(1.0f)));
  return __builtin_bit_cast(half2v, __hmul2(hv, r));
}

// async global->LDS, 16B per lane, zero VGPR cost. dst is wave-uniform base;
// HW writes lane i at dst + i*16B. src is per-lane. Respects exec mask.
__device__ __forceinline__ void gll16(const _Float16* src, _Float16* ldsDst){
  __builtin_amdgcn_global_load_lds(
      (const __attribute__((address_space(1))) uint32*)src,
      (__attribute__((address_space(3))) uint32*)ldsDst, 16, 0, 0);
}

// ---------------------------------------------------------------------------
// fp16 weight blob layout (element offsets):
//   0      stemW0..2 | 86016 w1 (cls/reg) | 196608 w2 | 307200 clsp_w
//   330240 wdT | 340608 regobj | 345216 dwbias | 346368 total
// ---------------------------------------------------------------------------
#define OFF_W1    86016
#define OFF_W2    196608
#define OFF_HEAD  307200
#define OFF_WDT   330240
#define OFF_ROBJ  340608
#define OFF_DWB   345216
#define WTOT      346368

// stem output, CHANNEL-GROUP-MAJOR: [g=12][n=134400][8ch]
#define NDW  134400

__global__ __launch_bounds__(256) void wconv_k(
    const float* __restrict__ s0, const float* __restrict__ s1,
    const float* __restrict__ s2, const float* __restrict__ cw1,
    const float* __restrict__ rw1, const float* __restrict__ cw2,
    const float* __restrict__ rw2, const float* __restrict__ chw,
    const float* __restrict__ cwd, const float* __restrict__ rwd,
    const float* __restrict__ rpw, const float* __restrict__ opw,
    const float* __restrict__ cbd, const float* __restrict__ rbd,
    _Float16* __restrict__ dst)
{
  int i = blockIdx.x*256 + threadIdx.x;
  if (i >= WTOT) return;
  float v;
  if (i < OFF_WDT) {
    const float* p; int off;
    if      (i < 12288)  { p = s0;  off = i; }
    else if (i < 36864)  { p = s1;  off = i - 12288; }
    else if (i < 86016)  { p = s2;  off = i - 36864; }
    else if (i < 141312) { p = cw1; off = i - 86016; }
    else if (i < 196608) { p = rw1; off = i - 141312; }
    else if (i < 251904) { p = cw2; off = i - 196608; }
    else if (i < 307200) { p = rw2; off = i - 251904; }
    else                 { p = chw; off = i - 307200; }
    v = p[off];
  } else if (i < OFF_ROBJ) {
    int rel = i - OFF_WDT;
    int br = rel / 5184; int r2 = rel - br*5184;
    int lvl = r2 / 1728; int r3 = r2 - lvl*1728;
    int j = r3 / 192;    int c = r3 - j*192;
    const float* wd = br ? rwd : cwd;
    v = wd[lvl*1728 + c*9 + j];
  } else if (i < OFF_DWB) {
    int rel = i - OFF_ROBJ;
    int lvl = rel / 1536; int r2 = rel - lvl*1536;
    int co = r2 / 96;     int k = r2 - co*96;
    v = (co < 4) ? rpw[lvl*384 + co*96 + k] : (co == 4 ? opw[lvl*96 + k] : 0.f);
  } else {
    int rel = i - OFF_DWB;
    int br = rel / 576;  int r2 = rel - br*576;
    int lvl = r2 / 192;  int c = r2 - lvl*192;
    v = (br ? rbd : cbd)[lvl*192 + c];
  }
  dst[i] = (_Float16)v;
}

// ---------------------------------------------------------------------------
// Stem GEMM from NCHW fp32, fp16 MFMA. Output CHANNEL-GROUP-MAJOR [g][n][8].
// ---------------------------------------------------------------------------
__global__ __launch_bounds__(256) void stem_k(
    const float* __restrict__ x0, const float* __restrict__ x1,
    const float* __restrict__ x2, const _Float16* __restrict__ Wb,
    const float* __restrict__ sb0, const float* __restrict__ sb1,
    const float* __restrict__ sb2, _Float16* __restrict__ Out)
{
  const int m0 = blockIdx.x << 7;
  const int lvl = (m0 < 102400) ? 0 : (m0 < 128000 ? 1 : 2);
  const int CIN = (lvl==0)?128:(lvl==1?256:512);
  const int HW  = (lvl==0)?6400:(lvl==1?1600:400);
  const int noff= (lvl==0)?0:(lvl==1?102400:128000);
  const float* X = (lvl==0)?x0:(lvl==1?x1:x2);
  const _Float16* Wl = Wb + ((lvl==0)?0:(lvl==1?12288:36864));
  const float* bias = (lvl==0)?sb0:(lvl==1?sb1:sb2);

  int t=threadIdx.x, lane=t&63, wv=t>>6, mr=lane&15, quad=lane>>4;

  int idx[2];
  #pragma unroll
  for (int nt=0; nt<2; ++nt) {
    int n = m0 + wv*32 + nt*16 + mr;
    int m = n - noff; int b_ = m / HW; int p = m - b_*HW;
    idx[nt] = (b_*CIN + quad*8)*HW + p;
  }
  const _Float16* Ap = Wl + mr*CIN + quad*8;

  floatx4 zero = {0.f,0.f,0.f,0.f};
  floatx4 acc[6][2];
  #pragma unroll
  for (int i=0;i<6;++i)
    #pragma unroll
    for (int j=0;j<2;++j) acc[i][j] = zero;

  for (int k=0; k<CIN; k+=32) {
    half8 a[6], b[2];
    #pragma unroll
    for (int mt=0; mt<6; ++mt) a[mt] = *(const half8*)(Ap + mt*16*CIN);
    #pragma unroll
    for (int nt=0; nt<2; ++nt) {
      float f[8];
      #pragma unroll
      for (int j=0;j<8;++j) f[j] = X[idx[nt] + j*HW];
      half2v* bh = (half2v*)&b[nt];
      #pragma unroll
      for (int j=0;j<4;++j) bh[j] = pkrtz(f[2*j], f[2*j+1]);
    }
    #pragma unroll
    for (int mt=0; mt<6; ++mt)
      #pragma unroll
      for (int nt=0; nt<2; ++nt)
        acc[mt][nt] = __builtin_amdgcn_mfma_f32_16x16x32_f16(a[mt], b[nt], acc[mt][nt], 0, 0, 0);
    Ap += 32;
    #pragma unroll
    for (int nt=0; nt<2; ++nt) idx[nt] += 32*HW;
  }

  #pragma unroll
  for (int mt=0; mt<6; ++mt) {
    float4 bv = *(const float4*)(bias + mt*16 + quad*4);
    int co = mt*16 + quad*4;
    int g = co >> 3; int h = co & 7;
    #pragma unroll
    for (int nt=0; nt<2; ++nt) {
      int pos = m0 + wv*32 + nt*16 + mr;
      half4v o;
      o[0] = (_Float16)silu_f(acc[mt][nt][0] + bv.x);
      o[1] = (_Float16)silu_f(acc[mt][nt][1] + bv.y);
      o[2] = (_Float16)silu_f(acc[mt][nt][2] + bv.z);
      o[3] = (_Float16)silu_f(acc[mt][nt][3] + bv.w);
      *(half4v*)(Out + g*NDW*8 + pos*8 + h) = o;
    }
  }
}

// ---------------------------------------------------------------------------
// MEGAFUSED v4 (r16 structure) with dw-weight LDS residency:
//  - wdT+dwb (3.84KB, block-wide reuse, quad-uniform) staged ONCE per block
//    via zero-VGPR global_load_lds; phase-2 weight reads become broadcast
//    ds_read (conflict-free) -- removes the per-k global-latency round that
//    the 64-VGPR allocator kept re-serializing.
//  - __launch_bounds__(256,3): VGPR cap ~170 so remaining loads stay in flight.
// LDS: wdl 1984 + halo 24*808 = 42.7KB -> 3 blocks/CU; ldsP aliases halo.
// grid (2144, 2): [0,1600) lvl0, [1600,2000) lvl1, [2000,2144) lvl2
// (overlapping 8x8 tiles on 20x20, y0,x0 in {0,6,12}; dup writes identical).
// ---------------------------------------------------------------------------
#define PSTRIDE 104
#define HS2 808
__global__ __launch_bounds__(256, 3) void xfuse_k(
    const _Float16* __restrict__ stemO, const _Float16* __restrict__ wbf,
    const float* __restrict__ b1c, const float* __restrict__ b1r,
    const float* __restrict__ b2_c, const float* __restrict__ b2_r,
    const float* __restrict__ hb, const float* __restrict__ rb,
    const float* __restrict__ ob, float* __restrict__ out)
{
  __shared__ _Float16 wdl[1984];         // dw weights [tap][192] | bias [192]
  __shared__ _Float16 halo[24*HS2];      // [g][100 entries][8ch] (+pad)
  _Float16* ldsP = halo;                 // alias after phase-2 barrier
  const int bz = blockIdx.y;
  const float* b2 = bz ? b2_r : b2_c;

  int orig = blockIdx.x;
  int bx = (orig & 7)*268 + (orig >> 3);   // bijective: 2144 = 8*268

  int lvl, W, HW, noff, a0;
  int b_, y0, x0;
  if (bx < 1600) {
    lvl = 0; W = 80; HW = 6400; noff = 0;      a0 = 0;
    b_ = bx / 100; int tl = bx - b_*100;
    y0 = (tl / 10) * 8; x0 = (tl - (tl/10)*10) * 8;
  } else if (bx < 2000) {
    lvl = 1; W = 40; HW = 1600; noff = 102400; a0 = 6400;
    int rel = bx - 1600; b_ = rel / 25; int tl = rel - b_*25;
    y0 = (tl / 5) * 8; x0 = (tl - (tl/5)*5) * 8;
  } else {
    lvl = 2; W = 20; HW = 400; noff = 128000; a0 = 8000;
    int rel = bx - 2000; b_ = rel / 9; int tl = rel - b_*9;
    int iy = tl / 3; int ix = tl - iy*3;
    y0 = iy*6; x0 = ix*6;                 // overlapping 8x8 tiles on 20x20
  }

  int t = threadIdx.x, lane = t & 63, wv = t >> 6;
  int mr = lane & 15, quad = lane >> 4;
  const int p = wv*16 + mr;              // this thread's tile-local position

  const _Float16* wT = wbf + OFF_WDT + bz*5184 + lvl*1728;
  const _Float16* bB = wbf + OFF_DWB + bz*576 + lvl*192;
  const _Float16* Ap = wbf + OFF_W2 + bz*55296 + lvl*18432 + mr*192 + quad*8;

  // ---- 0. stage dw weights+bias (1920 hw = 240 x 16B) into LDS, async ----
  {
    if (wv < 3) {
      gll16(wT + (wv*64 + lane)*8, wdl + wv*512);
    } else {
      if (lane < 24)
        gll16(wT + (192 + lane)*8, wdl + 1536);          // wdT chunks 192..215
      else if (lane < 48)
        gll16(bB + (lane - 24)*8, wdl + 1536);           // bias chunks 0..23 -> 1728..1919
    }
  }

  // this thread's global position n (center tile)
  const int n = noff + b_*HW + (y0 + (p>>3))*W + x0 + (p&7);

  // resid prefetch (consumed after phase 2)
  half4v rsv[6];
  #pragma unroll
  for (int mt=0; mt<6; ++mt) {
    int co = mt*16 + quad*4;
    int g = co >> 3; int h = co & 7;
    rsv[mt] = *(const half4v*)(stemO + g*(NDW*8) + n*8 + h);
  }

  // ---- 1. expand GEMM: W1 (reg-hoisted) x stem (direct global) -> halo ----
  {
    const _Float16* W1 = wbf + OFF_W1 + bz*55296 + lvl*18432;
    const float* bp1 = (bz ? b1r : b1c) + lvl*192;
    // hoist A-frags: 3 M-tiles x 3 k-steps
    half8 wf[3][3];
    #pragma unroll
    for (int m3 = 0; m3 < 3; ++m3)
      #pragma unroll
      for (int ks = 0; ks < 3; ++ks)
        wf[m3][ks] = *(const half8*)(W1 + ((wv*3+m3)*16 + mr)*96 + ks*32 + quad*8);

    #pragma unroll
    for (int nt = 0; nt < 7; ++nt) {
      int ee = nt*16 + mr;
      int e = ee < 100 ? ee : 99;
      int hy = e / 10, hx = e - hy*10;
      int ay = y0 - 1 + hy, ax = x0 - 1 + hx;
      bool oob = ((unsigned)ay >= (unsigned)W) || ((unsigned)ax >= (unsigned)W);
      int yy = ay < 0 ? 0 : (ay >= W ? W-1 : ay);
      int xx = ax < 0 ? 0 : (ax >= W ? W-1 : ax);
      int ne = noff + b_*HW + yy*W + xx;

      floatx4 acc[3];
      #pragma unroll
      for (int m3 = 0; m3 < 3; ++m3) acc[m3] = floatx4{0.f,0.f,0.f,0.f};
      #pragma unroll
      for (int ks = 0; ks < 3; ++ks) {
        half8 af = *(const half8*)(stemO + (ks*4+quad)*(NDW*8) + ne*8);
        #pragma unroll
        for (int m3 = 0; m3 < 3; ++m3)
          acc[m3] = __builtin_amdgcn_mfma_f32_16x16x32_f16(wf[m3][ks], af, acc[m3], 0, 0, 0);
      }
      if (ee < 100) {
        #pragma unroll
        for (int m3 = 0; m3 < 3; ++m3) {
          int co = (wv*3+m3)*16 + quad*4;
          float4 bv = *(const float4*)(bp1 + co);
          half4v o;
          if (oob) {
            o[0]=o[1]=o[2]=o[3]=(_Float16)0.f;
          } else {
            half2v p01 = silu_h2(pkrtz(acc[m3][0] + bv.x, acc[m3][1] + bv.y));
            half2v p23 = silu_h2(pkrtz(acc[m3][2] + bv.z, acc[m3][3] + bv.w));
            o[0]=p01[0]; o[1]=p01[1]; o[2]=p23[0]; o[3]=p23[1];
          }
          *(half4v*)(halo + (co>>3)*HS2 + ee*8 + (co&7)) = o;
        }
      }
    }
  }
  __syncthreads();   // halo complete + wdl staged (vmcnt drained)

  // ---- 2. fused dw + proj k-loop, taps + dw weights from LDS ----
  floatx4 pacc[6];
  #pragma unroll
  for (int j=0;j<6;++j) pacc[j] = floatx4{0.f,0.f,0.f,0.f};
  {
    const int ty = p >> 3, tx = p & 7;
    const _Float16* hb0 = halo + (ty*10 + tx)*8;   // entry (ty,tx) base
    for (int k = 0; k < 6; ++k) {
      const int g = 4*k + quad;
      const _Float16* hg = hb0 + g*HS2;

      half8 a[9], w[9];
      #pragma unroll
      for (int dy = 0; dy < 3; ++dy)
        #pragma unroll
        for (int dx = 0; dx < 3; ++dx)
          a[dy*3+dx] = *(const half8*)(hg + (dy*10 + dx)*8);
      #pragma unroll
      for (int tap = 0; tap < 9; ++tap)
        w[tap] = *(const half8*)(wdl + tap*192 + g*8);
      half8 bv8 = *(const half8*)(wdl + 1728 + g*8);
      half8 wfp[6];
      #pragma unroll
      for (int mt = 0; mt < 6; ++mt)
        wfp[mt] = *(const half8*)(Ap + mt*16*192 + k*32);

      half2v ac0 = {bv8[0], bv8[1]};
      half2v ac1 = {bv8[2], bv8[3]};
      half2v ac2 = {bv8[4], bv8[5]};
      half2v ac3 = {bv8[6], bv8[7]};
      #pragma unroll
      for (int tap = 0; tap < 9; ++tap) {
        ac0 += half2v{a[tap][0],a[tap][1]} * half2v{w[tap][0],w[tap][1]};
        ac1 += half2v{a[tap][2],a[tap][3]} * half2v{w[tap][2],w[tap][3]};
        ac2 += half2v{a[tap][4],a[tap][5]} * half2v{w[tap][4],w[tap][5]};
        ac3 += half2v{a[tap][6],a[tap][7]} * half2v{w[tap][6],w[tap][7]};
      }
      half8 af;
      {
        half2v* oh = (half2v*)&af;
        oh[0] = silu_h2(ac0);
        oh[1] = silu_h2(ac1);
        oh[2] = silu_h2(ac2);
        oh[3] = silu_h2(ac3);
      }
      #pragma unroll
      for (int mt = 0; mt < 6; ++mt)
        pacc[mt] = __builtin_amdgcn_mfma_f32_16x16x32_f16(wfp[mt], af, pacc[mt], 0, 0, 0);
    }
  }
  __syncthreads();   // halo reads done -> ldsP may overwrite

  // ---- 3. epilogue: + bias + prefetched residual -> ldsP [pos][co] ----
  {
    const float* bp2 = b2 + lvl*96;
    #pragma unroll
    for (int mt=0; mt<6; ++mt) {
      int co = mt*16 + quad*4;
      float4 bv = *(const float4*)(bp2 + co);
      half4v o;
      o[0] = (_Float16)(pacc[mt][0] + bv.x + (float)rsv[mt][0]);
      o[1] = (_Float16)(pacc[mt][1] + bv.y + (float)rsv[mt][1]);
      o[2] = (_Float16)(pacc[mt][2] + bv.z + (float)rsv[mt][2]);
      o[3] = (_Float16)(pacc[mt][3] + bv.w + (float)rsv[mt][3]);
      *(half4v*)(ldsP + p*PSTRIDE + co) = o;
    }
  }
  // heads read only this wave's 16 rows -> no barrier (same-wave ds ordering).

  // ---- heads ----
  if (bz == 0) {
    const _Float16* Bp = wbf + OFF_HEAD + lvl*7680 + mr*96 + quad*8;
    const float* bp = hb + lvl*80;
    floatx4 acc[5];
    #pragma unroll
    for (int j=0;j<5;++j) acc[j] = floatx4{0.f,0.f,0.f,0.f};

    #pragma unroll
    for (int k=0; k<3; ++k) {
      half8 a = *(const half8*)(ldsP + (wv*16 + mr)*PSTRIDE + k*32 + quad*8);
      half8 b[5];
      #pragma unroll
      for (int nt=0; nt<5; ++nt)
        b[nt] = *(const half8*)(Bp + nt*16*96 + k*32);
      #pragma unroll
      for (int nt=0; nt<5; ++nt)
        acc[nt] = __builtin_amdgcn_mfma_f32_16x16x32_f16(a, b[nt], acc[nt], 0, 0, 0);
    }

    #pragma unroll
    for (int nt=0; nt<5; ++nt) {
      int co = nt*16 + mr;
      float bv = bp[co];
      #pragma unroll
      for (int r=0; r<4; ++r) {
        int pq = wv*16 + quad*4 + r;       // tile-local position
        int rpp = (y0 + (pq>>3))*W + x0 + (pq&7);
        out[(b_*8400 + a0 + rpp)*85 + 5 + co] = sigm_f(acc[nt][r] + bv);
      }
    }
  } else {
    const _Float16* Bp = wbf + OFF_ROBJ + lvl*1536 + mr*96 + quad*8;
    float bv = (mr < 4) ? rb[lvl*4 + mr] : ((mr == 4) ? ob[lvl] : 0.f);
    float sc = (lvl==0) ? 8.f : (lvl==1 ? 16.f : 32.f);
    floatx4 acc = {0.f,0.f,0.f,0.f};
    #pragma unroll
    for (int k=0; k<3; ++k) {
      half8 a = *(const half8*)(ldsP + (wv*16 + mr)*PSTRIDE + k*32 + quad*8);
      half8 b = *(const half8*)(Bp + k*32);
      acc = __builtin_amdgcn_mfma_f32_16x16x32_f16(a, b, acc, 0, 0, 0);
    }
    #pragma unroll
    for (int r=0; r<4; ++r) {
      int pq = wv*16 + quad*4 + r;
      int yy = y0 + (pq>>3); int xx = x0 + (pq&7);
      int rpp = yy*W + xx;
      float v = acc[r] + bv;
      float o;
      if      (mr == 0) o = (v + (float)xx)*sc;
      else if (mr == 1) o = (v + (float)yy)*sc;
      else if (mr <  4) o = __expf(v)*sc;
      else              o = sigm_f(v);
      if (mr < 5)
        out[(b_*8400 + a0 + rpp)*85 + mr] = o;
    }
  }
}

extern "C" void kernel_launch(void* const* d_in, const int* in_sizes, int n_in,
                              void* d_out, int out_size, void* d_ws, size_t ws_size,
                              hipStream_t stream)
{
  bool dict = (in_sizes[1] == 96*128);
  const float* X[3]; const float* SW[3]; const float* SB[3];
  if (dict) {
    X[0]=(const float*)d_in[0]; SW[0]=(const float*)d_in[1]; SB[0]=(const float*)d_in[2];
    X[1]=(const float*)d_in[3]; SW[1]=(const float*)d_in[4]; SB[1]=(const float*)d_in[5];
    X[2]=(const float*)d_in[6]; SW[2]=(const float*)d_in[7]; SB[2]=(const float*)d_in[8];
  } else {
    X[0]=(const float*)d_in[0]; X[1]=(const float*)d_in[1]; X[2]=(const float*)d_in[2];
    SW[0]=(const float*)d_in[3]; SB[0]=(const float*)d_in[4];
    SW[1]=(const float*)d_in[5]; SB[1]=(const float*)d_in[6];
    SW[2]=(const float*)d_in[7]; SB[2]=(const float*)d_in[8];
  }
  const float* br_w1[2] = {(const float*)d_in[9],  (const float*)d_in[15]};
  const float* br_b1[2] = {(const float*)d_in[10], (const float*)d_in[16]};
  const float* br_wd[2] = {(const float*)d_in[11], (const float*)d_in[17]};
  const float* br_bd[2] = {(const float*)d_in[12], (const float*)d_in[18]};
  const float* br_w2[2] = {(const float*)d_in[13], (const float*)d_in[19]};
  const float* br_b2[2] = {(const float*)d_in[14], (const float*)d_in[20]};
  const float* clsp_w=(const float*)d_in[21]; const float* clsp_b=(const float*)d_in[22];
  const float* regp_w=(const float*)d_in[23]; const float* regp_b=(const float*)d_in[24];
  const float* objp_w=(const float*)d_in[25]; const float* objp_b=(const float*)d_in[26];

  float* out = (float*)d_out;

  // workspace (fp16 units): wbf 346,368 + stemO 12,902,400 = 26.5 MB
  _Float16* wbf   = (_Float16*)d_ws;
  _Float16* stemO = wbf + WTOT;

  // 1. weights/bias -> fp16 blob
  wconv_k<<<1353,256,0,stream>>>(SW[0],SW[1],SW[2],br_w1[0],br_w1[1],
                                 br_w2[0],br_w2[1],clsp_w,br_wd[0],br_wd[1],
                                 regp_w,objp_w,br_bd[0],br_bd[1],wbf);

  // 2. stem GEMM straight from NCHW fp32, channel-major output
  stem_k<<<1050,256,0,stream>>>(X[0],X[1],X[2],wbf,SB[0],SB[1],SB[2],stemO);

  // 3. MEGAFUSED expand + dw3x3 + project + residual + heads
  xfuse_k<<<dim3(2144,2),256,0,stream>>>(
      stemO, wbf, br_b1[0], br_b1[1], br_b2[0], br_b2[1],
      clsp_b, regp_b, objp_b, out);
}